// Round 4
// baseline (363.859 us; speedup 1.0000x reference)
//
#include <hip/hip_runtime.h>

#define N_PIX 16384   // 4 * 64 * 64

typedef float v2f __attribute__((ext_vector_type(2)));

// ---------------------------------------------------------------------------
// Cross-lane butterfly helpers: DPP for xor 1/2/8 (VALU pipe), ds_swizzle for
// xor 4/16, ds_bpermute for xor 32.
// ---------------------------------------------------------------------------
template<int C>
__device__ __forceinline__ float dppmov(float x) {
  return __int_as_float(__builtin_amdgcn_update_dpp(0, __float_as_int(x), C, 0xF, 0xF, true));
}
template<int IMM>
__device__ __forceinline__ float dswz(float x) {
  return __int_as_float(__builtin_amdgcn_ds_swizzle(__float_as_int(x), IMM));
}
__device__ __forceinline__ float bperm(float x, int a32) {
  return __int_as_float(__builtin_amdgcn_ds_bpermute(a32, __float_as_int(x)));
}
template<int M>
__device__ __forceinline__ float bfly(float x, int a32) {
  if constexpr (M == 1)       return dppmov<0xB1>(x);
  else if constexpr (M == 2)  return dppmov<0x4E>(x);
  else if constexpr (M == 8)  return dppmov<0x128>(x);
  else if constexpr (M == 4)  return dswz<0x101F>(x);
  else if constexpr (M == 16) return dswz<0x401F>(x);
  else                        return bperm(x, a32);
}
template<int M>
__device__ __forceinline__ v2f bfly2(v2f v, int a32) {
  v2f o; o.x = bfly<M>(v.x, a32); o.y = bfly<M>(v.y, a32); return o;
}
__device__ __forceinline__ float rdlane(float x, int l) {
  return __int_as_float(__builtin_amdgcn_readlane(__float_as_int(x), l));
}
__device__ __forceinline__ float rdfirst(float x) {
  return __int_as_float(__builtin_amdgcn_readfirstlane(__float_as_int(x)));
}
__device__ __forceinline__ v2f sp(float s) { v2f v; v.x = s; v.y = s; return v; }
__device__ __forceinline__ v2f vfma(v2f a, v2f b, v2f c) {
  return __builtin_elementwise_fma(a, b, c);
}

// ---------------------------------------------------------------------------
// State: 2 pixels per wave packed in v2f (.x = pixel A, .y = pixel B).
// amp index i = lane*4 + r. wire w<=5 <-> lane mask 32>>w; wire6 = r bit1;
// wire7 = r bit0.
// ---------------------------------------------------------------------------
template<int M, int CM>
__device__ __forceinline__ void crossg(v2f Sr[4], v2f Si[4],
    const float* __restrict__ g, int lane, int a32) {
  const bool hi = (lane & M) != 0;
  float fr, fi, gr, gi;
  if constexpr (CM == 0) {
    fr = hi ? g[6] : g[0]; fi = hi ? g[7] : g[1];
    gr = hi ? g[4] : g[2]; gi = hi ? g[5] : g[3];
  } else {
    const bool ct = (lane & CM) != 0;
    float f0r = hi ? g[6]  : g[0],  f0i = hi ? g[7]  : g[1];
    float g0r = hi ? g[4]  : g[2],  g0i = hi ? g[5]  : g[3];
    float f1r = hi ? g[14] : g[8],  f1i = hi ? g[15] : g[9];
    float g1r = hi ? g[12] : g[10], g1i = hi ? g[13] : g[11];
    fr = ct ? f1r : f0r; fi = ct ? f1i : f0i;
    gr = ct ? g1r : g0r; gi = ct ? g1i : g0i;
  }
  v2f vfr = sp(fr), vfi = sp(fi), vgr = sp(gr), vgi = sp(gi);
  v2f vfiN = sp(-fi), vgiN = sp(-gi);
#pragma unroll
  for (int r = 0; r < 4; ++r) {
    v2f pR = bfly2<M>(Sr[r], a32);
    v2f pI = bfly2<M>(Si[r], a32);
    v2f nR = vfma(vgiN, pI, vfma(vgr, pR, vfma(vfiN, Si[r], vfr * Sr[r])));
    v2f nI = vfma(vgi,  pR, vfma(vgr, pI, vfma(vfi,  Sr[r], vfr * Si[r])));
    Sr[r] = nR; Si[r] = nI;
  }
}

__device__ __forceinline__ void mixP(v2f& x0r, v2f& x0i, v2f& x1r, v2f& x1i,
    float m0r, float m0i, float m1r, float m1i,
    float m2r, float m2i, float m3r, float m3i) {
  v2f n0r = vfma(sp(-m1i), x1i, vfma(sp(m1r), x1r, vfma(sp(-m0i), x0i, sp(m0r) * x0r)));
  v2f n0i = vfma(sp( m1i), x1r, vfma(sp(m1r), x1i, vfma(sp( m0i), x0r, sp(m0r) * x0i)));
  v2f n1r = vfma(sp(-m3i), x1i, vfma(sp(m3r), x1r, vfma(sp(-m2i), x0i, sp(m2r) * x0r)));
  v2f n1i = vfma(sp( m3i), x1r, vfma(sp(m3r), x1i, vfma(sp( m2i), x0r, sp(m2r) * x0i)));
  x0r = n0r; x0i = n0i; x1r = n1r; x1i = n1i;
}

__device__ __forceinline__ void f6(v2f Sr[4], v2f Si[4],
    const float* __restrict__ g, int lane) {
  const bool ct = (lane & 1) != 0;
  float m[8];
#pragma unroll
  for (int j = 0; j < 8; ++j) m[j] = ct ? g[8 + j] : g[j];
  mixP(Sr[0], Si[0], Sr[2], Si[2], m[0],m[1],m[2],m[3],m[4],m[5],m[6],m[7]);
  mixP(Sr[1], Si[1], Sr[3], Si[3], m[0],m[1],m[2],m[3],m[4],m[5],m[6],m[7]);
}

__device__ __forceinline__ void f7(v2f Sr[4], v2f Si[4],
    const float* __restrict__ g) {
  mixP(Sr[0], Si[0], Sr[1], Si[1], g[0],g[1],g[2],g[3],g[4],g[5],g[6],g[7]);
  mixP(Sr[2], Si[2], Sr[3], Si[3], g[8],g[9],g[10],g[11],g[12],g[13],g[14],g[15]);
}

__device__ __forceinline__ void f8p(v2f Sr[4], v2f Si[4],
    const float* __restrict__ g, int lane, int a32) {
  const bool hi = (lane & 32) != 0;
  float fr[2], fi[2], gr[2], gi[2];
  fr[0] = hi ? g[6]  : g[0];  fi[0] = hi ? g[7]  : g[1];
  gr[0] = hi ? g[4]  : g[2];  gi[0] = hi ? g[5]  : g[3];
  fr[1] = hi ? g[14] : g[8];  fi[1] = hi ? g[15] : g[9];
  gr[1] = hi ? g[12] : g[10]; gi[1] = hi ? g[13] : g[11];
#pragma unroll
  for (int r = 0; r < 4; ++r) {
    const int m = r & 1;
    v2f pR = bfly2<32>(Sr[r], a32);
    v2f pI = bfly2<32>(Si[r], a32);
    v2f nR = vfma(sp(-gi[m]), pI, vfma(sp(gr[m]), pR, vfma(sp(-fi[m]), Si[r], sp(fr[m]) * Sr[r])));
    v2f nI = vfma(sp( gi[m]), pR, vfma(sp(gr[m]), pI, vfma(sp( fi[m]), Sr[r], sp(fr[m]) * Si[r])));
    Sr[r] = nR; Si[r] = nI;
  }
}

__device__ __forceinline__ void f8(v2f Sr[4], v2f Si[4],
    const float* __restrict__ g, int lane, int a32) {
  const bool hi = (lane & 32) != 0;
  float fr = hi ? g[6] : g[0], fi = hi ? g[7] : g[1];
  float gr = hi ? g[4] : g[2], gi = hi ? g[5] : g[3];
#pragma unroll
  for (int rr = 0; rr < 2; ++rr) {
    const int r = 2 * rr + 1;
    v2f pR = bfly2<32>(Sr[r], a32);
    v2f pI = bfly2<32>(Si[r], a32);
    v2f nR = vfma(sp(-gi), pI, vfma(sp(gr), pR, vfma(sp(-fi), Si[r], sp(fr) * Sr[r])));
    v2f nI = vfma(sp( gi), pR, vfma(sp(gr), pI, vfma(sp( fi), Sr[r], sp(fr) * Si[r])));
    Sr[r] = nR; Si[r] = nI;
  }
}

template<int M>
__device__ __forceinline__ void hstepP(v2f Sr[4], v2f Si[4], v2f sgn, int a32) {
#pragma unroll
  for (int r = 0; r < 4; ++r) {
    v2f pR = bfly2<M>(Sr[r], a32);
    v2f pI = bfly2<M>(Si[r], a32);
    Sr[r] = vfma(sgn, Sr[r], pR);
    Si[r] = vfma(sgn, Si[r], pI);
  }
}
__device__ __forceinline__ void hp(v2f& a, v2f& b) { v2f t = a; a = t + b; b = t - b; }
__device__ __forceinline__ void h_intraP(v2f Sr[4], v2f Si[4]) {
  hp(Sr[0], Sr[2]); hp(Si[0], Si[2]); hp(Sr[1], Sr[3]); hp(Si[1], Si[3]);
  hp(Sr[0], Sr[1]); hp(Si[0], Si[1]); hp(Sr[2], Sr[3]); hp(Si[2], Si[3]);
}

__device__ __forceinline__ void phaseY(v2f Sr[4], v2f Si[4], int lane) {
  const int pl = __popc(lane);
#pragma unroll
  for (int r = 0; r < 4; ++r) {
    const int pcr = (r == 0) ? 0 : ((r == 3) ? 2 : 1);
    const int q = (pl + pcr) & 3;
    const bool b0 = (q & 1) != 0;
    const bool b1 = (q & 2) != 0;
    const float sR = b1 ? -1.0f : 1.0f;
    const float sI = (b0 != b1) ? -1.0f : 1.0f;
    v2f Rs = b0 ? Si[r] : Sr[r];
    v2f Is = b0 ? Sr[r] : Si[r];
    Sr[r] = sp(sR) * Rs;
    Si[r] = sp(sI) * Is;
  }
}

// <Z_w> for both packed pixels; results wave-uniform via readlane.
__device__ __forceinline__ void measureP(const v2f Sr[4], const v2f Si[4],
    int lane, int a32, const float* sgv, float* mA, float* mB) {
  v2f P[4];
#pragma unroll
  for (int r = 0; r < 4; ++r) P[r] = vfma(Si[r], Si[r], Sr[r] * Sr[r]);
  v2f t01 = P[0] + P[1], t23 = P[2] + P[3];
  v2f a  = t01 + t23;
  v2f d1 = t01 - t23;                       // wire 6
  v2f d0 = (P[0] - P[1]) + (P[2] - P[3]);   // wire 7
  a = vfma(sp(sgv[0]), a, bfly2<1>(a, a32));
  a = vfma(sp(sgv[1]), a, bfly2<2>(a, a32));
  a = vfma(sp(sgv[2]), a, bfly2<4>(a, a32));
  a = vfma(sp(sgv[3]), a, bfly2<8>(a, a32));
  a = vfma(sp(sgv[4]), a, bfly2<16>(a, a32));
  a = vfma(sp(sgv[5]), a, bfly2<32>(a, a32));
  mA[0] = rdlane(a.x, 32); mA[1] = rdlane(a.x, 16); mA[2] = rdlane(a.x, 8);
  mA[3] = rdlane(a.x, 4);  mA[4] = rdlane(a.x, 2);  mA[5] = rdlane(a.x, 1);
  mB[0] = rdlane(a.y, 32); mB[1] = rdlane(a.y, 16); mB[2] = rdlane(a.y, 8);
  mB[3] = rdlane(a.y, 4);  mB[4] = rdlane(a.y, 2);  mB[5] = rdlane(a.y, 1);
  d1 = d1 + bfly2<1>(d1, a32);  d0 = d0 + bfly2<1>(d0, a32);
  d1 = d1 + bfly2<2>(d1, a32);  d0 = d0 + bfly2<2>(d0, a32);
  d1 = d1 + bfly2<4>(d1, a32);  d0 = d0 + bfly2<4>(d0, a32);
  d1 = d1 + bfly2<8>(d1, a32);  d0 = d0 + bfly2<8>(d0, a32);
  d1 = d1 + bfly2<16>(d1, a32); d0 = d0 + bfly2<16>(d0, a32);
  d1 = d1 + bfly2<32>(d1, a32); d0 = d0 + bfly2<32>(d0, a32);
  mA[6] = rdfirst(d1.x); mA[7] = rdfirst(d0.x);
  mB[6] = rdfirst(d1.y); mB[7] = rdfirst(d0.y);
}

// Measurement stage folded directly into the FC accumulator (m values become
// SGPRs; 8-float weight row loaded fresh per stage -> no persistent arrays).
__device__ __forceinline__ float fcStage(const v2f Sr[4], const v2f Si[4],
    int lane, int a32, const float* sgv, const float* __restrict__ wrow,
    bool selA, float accO) {
  float mA[8], mB[8];
  measureP(Sr, Si, lane, a32, sgv, mA, mB);
  const float4* w4 = reinterpret_cast<const float4*>(wrow);
  float4 w0 = w4[0], w1 = w4[1];
  float wj[8] = {w0.x, w0.y, w0.z, w0.w, w1.x, w1.y, w1.z, w1.w};
#pragma unroll
  for (int j = 0; j < 8; ++j)
    accO = fmaf(selA ? mA[j] : mB[j], wj[j], accO);
  return accO;
}

// ---------------------------------------------------------------------------
// Prep helpers (complex 2x2 product, row-major r,i interleaved).
// ---------------------------------------------------------------------------
__device__ __forceinline__ void mm2(const float* A, const float* B, float* D) {
  D[0] = A[0]*B[0] - A[1]*B[1] + A[2]*B[4] - A[3]*B[5];
  D[1] = A[0]*B[1] + A[1]*B[0] + A[2]*B[5] + A[3]*B[4];
  D[2] = A[0]*B[2] - A[1]*B[3] + A[2]*B[6] - A[3]*B[7];
  D[3] = A[0]*B[3] + A[1]*B[2] + A[2]*B[7] + A[3]*B[6];
  D[4] = A[4]*B[0] - A[5]*B[1] + A[6]*B[4] - A[7]*B[5];
  D[5] = A[4]*B[1] + A[5]*B[0] + A[6]*B[5] + A[7]*B[4];
  D[6] = A[4]*B[2] - A[5]*B[3] + A[6]*B[6] - A[7]*B[7];
  D[7] = A[4]*B[3] + A[5]*B[2] + A[6]*B[7] + A[7]*B[6];
}
__device__ __forceinline__ void u3fill(const float* src, float* o) {
  float th = src[0], ph = src[1], lam = src[2];
  float c = cosf(0.5f * th), s = sinf(0.5f * th);
  float cl = cosf(lam), sl = sinf(lam);
  float cp = cosf(ph), spv = sinf(ph);
  float cpl = cosf(ph + lam), spl = sinf(ph + lam);
  o[0] = c;        o[1] = 0.0f;
  o[2] = -cl * s;  o[3] = -sl * s;
  o[4] = cp * s;   o[5] = spv * s;
  o[6] = cpl * c;  o[7] = spl * c;
}

// ---------------------------------------------------------------------------
// Tiny prep kernel (1 block): fused gate matrices G (640 floats, layout as in
// round 3) + FC weights rearranged stage-major and pre-scaled:
// FCW2[(s*32+c)*8 + w] = fcw[c*24 + s*8 + w] * {1, 1/256, 1/65536}[s].
// ---------------------------------------------------------------------------
__global__ __launch_bounds__(128) void prep_kernel(
    const float* __restrict__ u3p, const float* __restrict__ cu3p,
    const float* __restrict__ fcw, float* __restrict__ G,
    float* __restrict__ FCW2) {
  __shared__ float Us[40][8];
  __shared__ float Cs[40][8];
  int t = threadIdx.x;
  if (t < 40) u3fill(u3p + t * 3, Us[t]);
  if (t >= 64 && t < 104) u3fill(cu3p + (t - 64) * 3, Cs[t - 64]);
  __syncthreads();
  if (t == 0) {
#pragma unroll
    for (int j = 0; j < 8; ++j) G[j] = Us[0][j];
  } else if (t < 36) {
    int j = t - 1, b = j / 7, k = j % 7;
    float* dst = G + 8 + b * 112 + k * 16;
    const float* U = Us[b * 8 + k + 1];
    const float* C = Cs[b * 8 + k];
#pragma unroll
    for (int q = 0; q < 8; ++q) dst[q] = U[q];
    mm2(C, U, dst + 8);
  } else if (t < 40) {
    int b = t - 36;
    float* dst = G + 568 + b * 16;
    const float* U = Us[(b + 1) * 8];
    const float* C = Cs[b * 8 + 7];
#pragma unroll
    for (int q = 0; q < 8; ++q) dst[q] = U[q];
    mm2(U, C, dst + 8);
  } else if (t == 40) {
#pragma unroll
    for (int j = 0; j < 8; ++j) G[632 + j] = Cs[39][j];
  }
  for (int i = t; i < 768; i += 128) {
    int s = i >> 8, cc = (i >> 3) & 31, wv = i & 7;
    float sc = (s == 0) ? 1.0f : ((s == 1) ? (1.0f / 256.0f) : (1.0f / 65536.0f));
    FCW2[i] = fcw[cc * 24 + s * 8 + wv] * sc;
  }
}

// ---------------------------------------------------------------------------
// Fused conv + quantum simulator: 2 pixels per wave64, packed fp32.
// Conv lane layout: icg = lane&3, oc = (lane>>2)&7, px = lane>>5; each lane
// covers 4 input channels x 9 taps, DPP xor1/xor2-reduce over icg, readlane
// broadcast of the 16 angles.
// ---------------------------------------------------------------------------
__global__ __launch_bounds__(256, 6) void qconv_kernel(
    const float* __restrict__ x, const float* __restrict__ cw,
    const float* __restrict__ cb, const float* __restrict__ G,
    const float* __restrict__ FCW2, const float* __restrict__ fcb,
    float* __restrict__ out) {
  const int lane = threadIdx.x & 63;
  const int a32 = ((lane ^ 32) << 2);
  const int wid = __builtin_amdgcn_readfirstlane(
      (int)((blockIdx.x * blockDim.x + threadIdx.x) >> 6));
  const int p0 = wid * 2;

  float sgv[6];
#pragma unroll
  for (int k = 0; k < 6; ++k) sgv[k] = (lane & (1 << k)) ? -1.0f : 1.0f;

  // ---- conv: each lane accumulates 4 ic x 9 taps for its (px, oc) ----
  float angAcc;
  {
    const int icg = lane & 3;
    const int oc  = (lane >> 2) & 7;
    const int px  = lane >> 5;
    const int p   = p0 + px;
    const int b   = p >> 12;
    const int hh  = (p >> 6) & 63;
    const int wim = p & 63;
    const float* wb = cw + (oc * 16 + icg * 4) * 9;   // 36 contiguous, 16B-aligned
    float wt[36];
    const float4* wb4 = reinterpret_cast<const float4*>(wb);
#pragma unroll
    for (int q = 0; q < 9; ++q) {
      float4 tv = wb4[q];
      wt[q*4+0] = tv.x; wt[q*4+1] = tv.y; wt[q*4+2] = tv.z; wt[q*4+3] = tv.w;
    }
    const float* xb = x + (b * 16 + icg * 4) * 4096;
    float acc = 0.0f;
#pragma unroll
    for (int il = 0; il < 4; ++il) {
#pragma unroll
      for (int kh = 0; kh < 3; ++kh) {
        int ih = hh + kh - 1;
        bool rok = (unsigned)ih < 64u;
        int ihc = rok ? ih : 0;
#pragma unroll
        for (int kw = 0; kw < 3; ++kw) {
          int iw = wim + kw - 1;
          bool ok = rok && ((unsigned)iw < 64u);
          int iwc = ((unsigned)iw < 64u) ? iw : 0;
          float xv = xb[il * 4096 + ihc * 64 + iwc];
          acc = fmaf(ok ? xv : 0.0f, wt[il * 9 + kh * 3 + kw], acc);
        }
      }
    }
    acc += bfly<1>(acc, 0);   // DPP reduce over icg bit0
    acc += bfly<2>(acc, 0);   // and bit1
    angAcc = acc + cb[oc];
  }

  // ---- broadcast the 16 angles, build product state ----
  float cA[8], sA[8], cB[8], sB[8];
#pragma unroll
  for (int w = 0; w < 8; ++w) {
    float aa = 0.5f * rdlane(angAcc, w * 4);        // px A
    float ab = 0.5f * rdlane(angAcc, 32 + w * 4);   // px B
    __sincosf(aa, &sA[w], &cA[w]);
    __sincosf(ab, &sB[w], &cB[w]);
  }
  v2f Sr[4], Si[4];
  {
    float fA = ((lane & 32) ? sA[0] : cA[0]) * ((lane & 16) ? sA[1] : cA[1]);
    fA *= ((lane & 8) ? sA[2] : cA[2]);
    fA *= ((lane & 4) ? sA[3] : cA[3]);
    fA *= ((lane & 2) ? sA[4] : cA[4]);
    fA *= ((lane & 1) ? sA[5] : cA[5]);
    float fB = ((lane & 32) ? sB[0] : cB[0]) * ((lane & 16) ? sB[1] : cB[1]);
    fB *= ((lane & 8) ? sB[2] : cB[2]);
    fB *= ((lane & 4) ? sB[3] : cB[3]);
    fB *= ((lane & 2) ? sB[4] : cB[4]);
    fB *= ((lane & 1) ? sB[5] : cB[5]);
    Sr[0].x = fA * (cA[6]*cA[7]); Sr[0].y = fB * (cB[6]*cB[7]);
    Sr[1].x = fA * (cA[6]*sA[7]); Sr[1].y = fB * (cB[6]*sB[7]);
    Sr[2].x = fA * (sA[6]*cA[7]); Sr[2].y = fB * (sB[6]*cB[7]);
    Sr[3].x = fA * (sA[6]*sA[7]); Sr[3].y = fB * (sB[6]*sB[7]);
    Si[0] = sp(0.0f); Si[1] = sp(0.0f); Si[2] = sp(0.0f); Si[3] = sp(0.0f);
  }

  // ---- fused circuit: F0, per block F1..F7 (+F8' into next block), F8 ----
  crossg<32, 0>(Sr, Si, G, lane, a32);
  for (int b = 0; b < 5; ++b) {
    const float* base = G + 8 + b * 112;
    crossg<16, 32>(Sr, Si, base +  0, lane, a32);
    crossg<8, 16> (Sr, Si, base + 16, lane, a32);
    crossg<4, 8>  (Sr, Si, base + 32, lane, a32);
    crossg<2, 4>  (Sr, Si, base + 48, lane, a32);
    crossg<1, 2>  (Sr, Si, base + 64, lane, a32);
    f6(Sr, Si, base + 80, lane);
    f7(Sr, Si, base + 96);
    if (b < 4) f8p(Sr, Si, G + 568 + b * 16, lane, a32);
  }
  f8(Sr, Si, G + 632, lane, a32);

  // ---- measurements with immediate FC fold ----
  const bool selA = lane < 32;
  const int c = lane & 31;
  float accO = fcb[c];
  accO = fcStage(Sr, Si, lane, a32, sgv, FCW2 + (0 * 32 + c) * 8, selA, accO);
  hstepP<1>(Sr, Si, sp(sgv[0]), a32);
  hstepP<2>(Sr, Si, sp(sgv[1]), a32);
  hstepP<4>(Sr, Si, sp(sgv[2]), a32);
  hstepP<8>(Sr, Si, sp(sgv[3]), a32);
  hstepP<16>(Sr, Si, sp(sgv[4]), a32);
  hstepP<32>(Sr, Si, sp(sgv[5]), a32);
  h_intraP(Sr, Si);
  accO = fcStage(Sr, Si, lane, a32, sgv, FCW2 + (1 * 32 + c) * 8, selA, accO);
  phaseY(Sr, Si, lane);
  hstepP<1>(Sr, Si, sp(sgv[0]), a32);
  hstepP<2>(Sr, Si, sp(sgv[1]), a32);
  hstepP<4>(Sr, Si, sp(sgv[2]), a32);
  hstepP<8>(Sr, Si, sp(sgv[3]), a32);
  hstepP<16>(Sr, Si, sp(sgv[4]), a32);
  hstepP<32>(Sr, Si, sp(sgv[5]), a32);
  h_intraP(Sr, Si);
  accO = fcStage(Sr, Si, lane, a32, sgv, FCW2 + (2 * 32 + c) * 8, selA, accO);

  // out[b, c, h, w]; lanes 0-31 -> p0, lanes 32-63 -> p1.
  int p = selA ? p0 : (p0 + 1);
  out[(p >> 12) * 131072 + c * 4096 + (p & 4095)] = accO;
}

extern "C" void kernel_launch(void* const* d_in, const int* in_sizes, int n_in,
                              void* d_out, int out_size, void* d_ws, size_t ws_size,
                              hipStream_t stream) {
  const float* x      = (const float*)d_in[0];
  const float* conv_w = (const float*)d_in[1];
  const float* conv_b = (const float*)d_in[2];
  const float* u3p    = (const float*)d_in[3];
  const float* cu3p   = (const float*)d_in[4];
  const float* fcw    = (const float*)d_in[5];
  const float* fcb    = (const float*)d_in[6];
  float* out = (float*)d_out;

  float* ws   = (float*)d_ws;
  float* G    = ws;          // 640 (fused gate matrices)
  float* FCW2 = ws + 640;    // 768 (stage-major, pre-scaled)

  prep_kernel<<<1, 128, 0, stream>>>(u3p, cu3p, fcw, G, FCW2);
  qconv_kernel<<<2048, 256, 0, stream>>>(x, conv_w, conv_b, G, FCW2, fcb, out);
}

// Round 5
// 138.269 us; speedup vs baseline: 2.6315x; 2.6315x over previous
//
#include <hip/hip_runtime.h>

#define N_PIX 16384   // 4 * 64 * 64

typedef float v2f __attribute__((ext_vector_type(2)));

// ---------------------------------------------------------------------------
// Cross-lane butterfly helpers: DPP for xor 1/2/8 (VALU pipe), ds_swizzle for
// xor 4/16, ds_bpermute for xor 32.
// ---------------------------------------------------------------------------
template<int C>
__device__ __forceinline__ float dppmov(float x) {
  return __int_as_float(__builtin_amdgcn_update_dpp(0, __float_as_int(x), C, 0xF, 0xF, true));
}
template<int IMM>
__device__ __forceinline__ float dswz(float x) {
  return __int_as_float(__builtin_amdgcn_ds_swizzle(__float_as_int(x), IMM));
}
__device__ __forceinline__ float bperm(float x, int a32) {
  return __int_as_float(__builtin_amdgcn_ds_bpermute(a32, __float_as_int(x)));
}
template<int M>
__device__ __forceinline__ float bfly(float x, int a32) {
  if constexpr (M == 1)       return dppmov<0xB1>(x);
  else if constexpr (M == 2)  return dppmov<0x4E>(x);
  else if constexpr (M == 8)  return dppmov<0x128>(x);
  else if constexpr (M == 4)  return dswz<0x101F>(x);
  else if constexpr (M == 16) return dswz<0x401F>(x);
  else                        return bperm(x, a32);
}
template<int M>
__device__ __forceinline__ v2f bfly2(v2f v, int a32) {
  v2f o; o.x = bfly<M>(v.x, a32); o.y = bfly<M>(v.y, a32); return o;
}
__device__ __forceinline__ float rdlane(float x, int l) {
  return __int_as_float(__builtin_amdgcn_readlane(__float_as_int(x), l));
}
__device__ __forceinline__ float rdfirst(float x) {
  return __int_as_float(__builtin_amdgcn_readfirstlane(__float_as_int(x)));
}
__device__ __forceinline__ v2f sp(float s) { v2f v; v.x = s; v.y = s; return v; }
__device__ __forceinline__ v2f vfma(v2f a, v2f b, v2f c) {
  return __builtin_elementwise_fma(a, b, c);
}

// ---------------------------------------------------------------------------
// State: 2 pixels per wave packed in v2f (.x = pixel A, .y = pixel B).
// amp index i = lane*4 + r. wire w<=5 <-> lane mask 32>>w; wire6 = r bit1;
// wire7 = r bit0.
// ---------------------------------------------------------------------------
template<int M, int CM>
__device__ __forceinline__ void crossg(v2f Sr[4], v2f Si[4],
    const float* __restrict__ g, int lane, int a32) {
  const bool hi = (lane & M) != 0;
  float fr, fi, gr, gi;
  if constexpr (CM == 0) {
    fr = hi ? g[6] : g[0]; fi = hi ? g[7] : g[1];
    gr = hi ? g[4] : g[2]; gi = hi ? g[5] : g[3];
  } else {
    const bool ct = (lane & CM) != 0;
    float f0r = hi ? g[6]  : g[0],  f0i = hi ? g[7]  : g[1];
    float g0r = hi ? g[4]  : g[2],  g0i = hi ? g[5]  : g[3];
    float f1r = hi ? g[14] : g[8],  f1i = hi ? g[15] : g[9];
    float g1r = hi ? g[12] : g[10], g1i = hi ? g[13] : g[11];
    fr = ct ? f1r : f0r; fi = ct ? f1i : f0i;
    gr = ct ? g1r : g0r; gi = ct ? g1i : g0i;
  }
  v2f vfr = sp(fr), vfi = sp(fi), vgr = sp(gr), vgi = sp(gi);
  v2f vfiN = sp(-fi), vgiN = sp(-gi);
#pragma unroll
  for (int r = 0; r < 4; ++r) {
    v2f pR = bfly2<M>(Sr[r], a32);
    v2f pI = bfly2<M>(Si[r], a32);
    v2f nR = vfma(vgiN, pI, vfma(vgr, pR, vfma(vfiN, Si[r], vfr * Sr[r])));
    v2f nI = vfma(vgi,  pR, vfma(vgr, pI, vfma(vfi,  Sr[r], vfr * Si[r])));
    Sr[r] = nR; Si[r] = nI;
  }
}

__device__ __forceinline__ void mixP(v2f& x0r, v2f& x0i, v2f& x1r, v2f& x1i,
    float m0r, float m0i, float m1r, float m1i,
    float m2r, float m2i, float m3r, float m3i) {
  v2f n0r = vfma(sp(-m1i), x1i, vfma(sp(m1r), x1r, vfma(sp(-m0i), x0i, sp(m0r) * x0r)));
  v2f n0i = vfma(sp( m1i), x1r, vfma(sp(m1r), x1i, vfma(sp( m0i), x0r, sp(m0r) * x0i)));
  v2f n1r = vfma(sp(-m3i), x1i, vfma(sp(m3r), x1r, vfma(sp(-m2i), x0i, sp(m2r) * x0r)));
  v2f n1i = vfma(sp( m3i), x1r, vfma(sp(m3r), x1i, vfma(sp( m2i), x0r, sp(m2r) * x0i)));
  x0r = n0r; x0i = n0i; x1r = n1r; x1i = n1i;
}

__device__ __forceinline__ void f6(v2f Sr[4], v2f Si[4],
    const float* __restrict__ g, int lane) {
  const bool ct = (lane & 1) != 0;
  float m[8];
#pragma unroll
  for (int j = 0; j < 8; ++j) m[j] = ct ? g[8 + j] : g[j];
  mixP(Sr[0], Si[0], Sr[2], Si[2], m[0],m[1],m[2],m[3],m[4],m[5],m[6],m[7]);
  mixP(Sr[1], Si[1], Sr[3], Si[3], m[0],m[1],m[2],m[3],m[4],m[5],m[6],m[7]);
}

__device__ __forceinline__ void f7(v2f Sr[4], v2f Si[4],
    const float* __restrict__ g) {
  mixP(Sr[0], Si[0], Sr[1], Si[1], g[0],g[1],g[2],g[3],g[4],g[5],g[6],g[7]);
  mixP(Sr[2], Si[2], Sr[3], Si[3], g[8],g[9],g[10],g[11],g[12],g[13],g[14],g[15]);
}

__device__ __forceinline__ void f8p(v2f Sr[4], v2f Si[4],
    const float* __restrict__ g, int lane, int a32) {
  const bool hi = (lane & 32) != 0;
  float fr[2], fi[2], gr[2], gi[2];
  fr[0] = hi ? g[6]  : g[0];  fi[0] = hi ? g[7]  : g[1];
  gr[0] = hi ? g[4]  : g[2];  gi[0] = hi ? g[5]  : g[3];
  fr[1] = hi ? g[14] : g[8];  fi[1] = hi ? g[15] : g[9];
  gr[1] = hi ? g[12] : g[10]; gi[1] = hi ? g[13] : g[11];
#pragma unroll
  for (int r = 0; r < 4; ++r) {
    const int m = r & 1;
    v2f pR = bfly2<32>(Sr[r], a32);
    v2f pI = bfly2<32>(Si[r], a32);
    v2f nR = vfma(sp(-gi[m]), pI, vfma(sp(gr[m]), pR, vfma(sp(-fi[m]), Si[r], sp(fr[m]) * Sr[r])));
    v2f nI = vfma(sp( gi[m]), pR, vfma(sp(gr[m]), pI, vfma(sp( fi[m]), Sr[r], sp(fr[m]) * Si[r])));
    Sr[r] = nR; Si[r] = nI;
  }
}

__device__ __forceinline__ void f8(v2f Sr[4], v2f Si[4],
    const float* __restrict__ g, int lane, int a32) {
  const bool hi = (lane & 32) != 0;
  float fr = hi ? g[6] : g[0], fi = hi ? g[7] : g[1];
  float gr = hi ? g[4] : g[2], gi = hi ? g[5] : g[3];
#pragma unroll
  for (int rr = 0; rr < 2; ++rr) {
    const int r = 2 * rr + 1;
    v2f pR = bfly2<32>(Sr[r], a32);
    v2f pI = bfly2<32>(Si[r], a32);
    v2f nR = vfma(sp(-gi), pI, vfma(sp(gr), pR, vfma(sp(-fi), Si[r], sp(fr) * Sr[r])));
    v2f nI = vfma(sp( gi), pR, vfma(sp(gr), pI, vfma(sp( fi), Sr[r], sp(fr) * Si[r])));
    Sr[r] = nR; Si[r] = nI;
  }
}

template<int M>
__device__ __forceinline__ void hstepP(v2f Sr[4], v2f Si[4], v2f sgn, int a32) {
#pragma unroll
  for (int r = 0; r < 4; ++r) {
    v2f pR = bfly2<M>(Sr[r], a32);
    v2f pI = bfly2<M>(Si[r], a32);
    Sr[r] = vfma(sgn, Sr[r], pR);
    Si[r] = vfma(sgn, Si[r], pI);
  }
}
__device__ __forceinline__ void hp(v2f& a, v2f& b) { v2f t = a; a = t + b; b = t - b; }
__device__ __forceinline__ void h_intraP(v2f Sr[4], v2f Si[4]) {
  hp(Sr[0], Sr[2]); hp(Si[0], Si[2]); hp(Sr[1], Sr[3]); hp(Si[1], Si[3]);
  hp(Sr[0], Sr[1]); hp(Si[0], Si[1]); hp(Sr[2], Sr[3]); hp(Si[2], Si[3]);
}

__device__ __forceinline__ void phaseY(v2f Sr[4], v2f Si[4], int lane) {
  const int pl = __popc(lane);
#pragma unroll
  for (int r = 0; r < 4; ++r) {
    const int pcr = (r == 0) ? 0 : ((r == 3) ? 2 : 1);
    const int q = (pl + pcr) & 3;
    const bool b0 = (q & 1) != 0;
    const bool b1 = (q & 2) != 0;
    const float sR = b1 ? -1.0f : 1.0f;
    const float sI = (b0 != b1) ? -1.0f : 1.0f;
    v2f Rs = b0 ? Si[r] : Sr[r];
    v2f Is = b0 ? Sr[r] : Si[r];
    Sr[r] = sp(sR) * Rs;
    Si[r] = sp(sI) * Is;
  }
}

// <Z_w> for both packed pixels; results wave-uniform via readlane.
__device__ __forceinline__ void measureP(const v2f Sr[4], const v2f Si[4],
    int lane, int a32, const float* sgv, float* mA, float* mB) {
  v2f P[4];
#pragma unroll
  for (int r = 0; r < 4; ++r) P[r] = vfma(Si[r], Si[r], Sr[r] * Sr[r]);
  v2f t01 = P[0] + P[1], t23 = P[2] + P[3];
  v2f a  = t01 + t23;
  v2f d1 = t01 - t23;                       // wire 6
  v2f d0 = (P[0] - P[1]) + (P[2] - P[3]);   // wire 7
  a = vfma(sp(sgv[0]), a, bfly2<1>(a, a32));
  a = vfma(sp(sgv[1]), a, bfly2<2>(a, a32));
  a = vfma(sp(sgv[2]), a, bfly2<4>(a, a32));
  a = vfma(sp(sgv[3]), a, bfly2<8>(a, a32));
  a = vfma(sp(sgv[4]), a, bfly2<16>(a, a32));
  a = vfma(sp(sgv[5]), a, bfly2<32>(a, a32));
  mA[0] = rdlane(a.x, 32); mA[1] = rdlane(a.x, 16); mA[2] = rdlane(a.x, 8);
  mA[3] = rdlane(a.x, 4);  mA[4] = rdlane(a.x, 2);  mA[5] = rdlane(a.x, 1);
  mB[0] = rdlane(a.y, 32); mB[1] = rdlane(a.y, 16); mB[2] = rdlane(a.y, 8);
  mB[3] = rdlane(a.y, 4);  mB[4] = rdlane(a.y, 2);  mB[5] = rdlane(a.y, 1);
  d1 = d1 + bfly2<1>(d1, a32);  d0 = d0 + bfly2<1>(d0, a32);
  d1 = d1 + bfly2<2>(d1, a32);  d0 = d0 + bfly2<2>(d0, a32);
  d1 = d1 + bfly2<4>(d1, a32);  d0 = d0 + bfly2<4>(d0, a32);
  d1 = d1 + bfly2<8>(d1, a32);  d0 = d0 + bfly2<8>(d0, a32);
  d1 = d1 + bfly2<16>(d1, a32); d0 = d0 + bfly2<16>(d0, a32);
  d1 = d1 + bfly2<32>(d1, a32); d0 = d0 + bfly2<32>(d0, a32);
  mA[6] = rdfirst(d1.x); mA[7] = rdfirst(d0.x);
  mB[6] = rdfirst(d1.y); mB[7] = rdfirst(d0.y);
}

// Measurement stage folded directly into the FC accumulator.
__device__ __forceinline__ float fcStage(const v2f Sr[4], const v2f Si[4],
    int lane, int a32, const float* sgv, const float* __restrict__ wrow,
    bool selA, float accO) {
  float mA[8], mB[8];
  measureP(Sr, Si, lane, a32, sgv, mA, mB);
  const float4* w4 = reinterpret_cast<const float4*>(wrow);
  float4 w0 = w4[0], w1 = w4[1];
  float wj[8] = {w0.x, w0.y, w0.z, w0.w, w1.x, w1.y, w1.z, w1.w};
#pragma unroll
  for (int j = 0; j < 8; ++j)
    accO = fmaf(selA ? mA[j] : mB[j], wj[j], accO);
  return accO;
}

// ---------------------------------------------------------------------------
// Prep helpers (complex 2x2 product, row-major r,i interleaved).
// ---------------------------------------------------------------------------
__device__ __forceinline__ void mm2(const float* A, const float* B, float* D) {
  D[0] = A[0]*B[0] - A[1]*B[1] + A[2]*B[4] - A[3]*B[5];
  D[1] = A[0]*B[1] + A[1]*B[0] + A[2]*B[5] + A[3]*B[4];
  D[2] = A[0]*B[2] - A[1]*B[3] + A[2]*B[6] - A[3]*B[7];
  D[3] = A[0]*B[3] + A[1]*B[2] + A[2]*B[7] + A[3]*B[6];
  D[4] = A[4]*B[0] - A[5]*B[1] + A[6]*B[4] - A[7]*B[5];
  D[5] = A[4]*B[1] + A[5]*B[0] + A[6]*B[5] + A[7]*B[4];
  D[6] = A[4]*B[2] - A[5]*B[3] + A[6]*B[6] - A[7]*B[7];
  D[7] = A[4]*B[3] + A[5]*B[2] + A[6]*B[7] + A[7]*B[6];
}
__device__ __forceinline__ void u3fill(const float* src, float* o) {
  float th = src[0], ph = src[1], lam = src[2];
  float c = cosf(0.5f * th), s = sinf(0.5f * th);
  float cl = cosf(lam), sl = sinf(lam);
  float cp = cosf(ph), spv = sinf(ph);
  float cpl = cosf(ph + lam), spl = sinf(ph + lam);
  o[0] = c;        o[1] = 0.0f;
  o[2] = -cl * s;  o[3] = -sl * s;
  o[4] = cp * s;   o[5] = spv * s;
  o[6] = cpl * c;  o[7] = spl * c;
}

// ---------------------------------------------------------------------------
// Tiny prep kernel (1 block): fused gate matrices G (640 floats) + FC weights
// stage-major, pre-scaled: FCW2[(s*32+c)*8+w] = fcw[c*24+s*8+w]*{1,2^-8,2^-16}.
// ---------------------------------------------------------------------------
__global__ __launch_bounds__(128) void prep_kernel(
    const float* __restrict__ u3p, const float* __restrict__ cu3p,
    const float* __restrict__ fcw, float* __restrict__ G,
    float* __restrict__ FCW2) {
  __shared__ float Us[40][8];
  __shared__ float Cs[40][8];
  int t = threadIdx.x;
  if (t < 40) u3fill(u3p + t * 3, Us[t]);
  if (t >= 64 && t < 104) u3fill(cu3p + (t - 64) * 3, Cs[t - 64]);
  __syncthreads();
  if (t == 0) {
#pragma unroll
    for (int j = 0; j < 8; ++j) G[j] = Us[0][j];
  } else if (t < 36) {
    int j = t - 1, b = j / 7, k = j % 7;
    float* dst = G + 8 + b * 112 + k * 16;
    const float* U = Us[b * 8 + k + 1];
    const float* C = Cs[b * 8 + k];
#pragma unroll
    for (int q = 0; q < 8; ++q) dst[q] = U[q];
    mm2(C, U, dst + 8);
  } else if (t < 40) {
    int b = t - 36;
    float* dst = G + 568 + b * 16;
    const float* U = Us[(b + 1) * 8];
    const float* C = Cs[b * 8 + 7];
#pragma unroll
    for (int q = 0; q < 8; ++q) dst[q] = U[q];
    mm2(U, C, dst + 8);
  } else if (t == 40) {
#pragma unroll
    for (int j = 0; j < 8; ++j) G[632 + j] = Cs[39][j];
  }
  for (int i = t; i < 768; i += 128) {
    int s = i >> 8, cc = (i >> 3) & 31, wv = i & 7;
    float sc = (s == 0) ? 1.0f : ((s == 1) ? (1.0f / 256.0f) : (1.0f / 65536.0f));
    FCW2[i] = fcw[cc * 24 + s * 8 + wv] * sc;
  }
}

// ---------------------------------------------------------------------------
// Fused conv + quantum simulator: 2 pixels per wave64, packed fp32.
// NOTE: plain __launch_bounds__(256) — round-4's (256,6) capped VGPR at 40 and
// produced 1.2 GB of scratch spills. Conv staging kept low-pressure: weights
// loaded inline per ic (no 36-float cache), il-loop unrolled 2x.
// ---------------------------------------------------------------------------
__global__ __launch_bounds__(256) void qconv_kernel(
    const float* __restrict__ x, const float* __restrict__ cw,
    const float* __restrict__ cb, const float* __restrict__ G,
    const float* __restrict__ FCW2, const float* __restrict__ fcb,
    float* __restrict__ out) {
  const int lane = threadIdx.x & 63;
  const int a32 = ((lane ^ 32) << 2);
  const int wid = __builtin_amdgcn_readfirstlane(
      (int)((blockIdx.x * blockDim.x + threadIdx.x) >> 6));
  const int p0 = wid * 2;

  float sgv[6];
#pragma unroll
  for (int k = 0; k < 6; ++k) sgv[k] = (lane & (1 << k)) ? -1.0f : 1.0f;

  // ---- conv: each lane accumulates 4 ic x 9 taps for its (px, oc) ----
  float angAcc;
  {
    const int icg = lane & 3;
    const int oc  = (lane >> 2) & 7;
    const int px  = lane >> 5;
    const int p   = p0 + px;
    const int b   = p >> 12;
    const int hh  = (p >> 6) & 63;
    const int wim = p & 63;
    float acc = 0.0f;
#pragma unroll 2
    for (int il = 0; il < 4; ++il) {
      const int ic = icg * 4 + il;
      const float* wp = cw + (oc * 16 + ic) * 9;
      const float* xp = x + (b * 16 + ic) * 4096;
#pragma unroll
      for (int kh = 0; kh < 3; ++kh) {
        int ih = hh + kh - 1;
        bool rok = (unsigned)ih < 64u;
        int ihc = rok ? ih : 0;
#pragma unroll
        for (int kw = 0; kw < 3; ++kw) {
          int iw = wim + kw - 1;
          bool ok = rok && ((unsigned)iw < 64u);
          int iwc = ((unsigned)iw < 64u) ? iw : 0;
          float xv = xp[ihc * 64 + iwc];
          acc = fmaf(ok ? xv : 0.0f, wp[kh * 3 + kw], acc);
        }
      }
    }
    acc += bfly<1>(acc, 0);   // DPP reduce over icg bit0
    acc += bfly<2>(acc, 0);   // and bit1
    angAcc = acc + cb[oc];
  }

  // ---- broadcast the 16 angles, build product state ----
  float cA[8], sA[8], cB[8], sB[8];
#pragma unroll
  for (int w = 0; w < 8; ++w) {
    float aa = 0.5f * rdlane(angAcc, w * 4);        // px A
    float ab = 0.5f * rdlane(angAcc, 32 + w * 4);   // px B
    __sincosf(aa, &sA[w], &cA[w]);
    __sincosf(ab, &sB[w], &cB[w]);
  }
  v2f Sr[4], Si[4];
  {
    float fA = ((lane & 32) ? sA[0] : cA[0]) * ((lane & 16) ? sA[1] : cA[1]);
    fA *= ((lane & 8) ? sA[2] : cA[2]);
    fA *= ((lane & 4) ? sA[3] : cA[3]);
    fA *= ((lane & 2) ? sA[4] : cA[4]);
    fA *= ((lane & 1) ? sA[5] : cA[5]);
    float fB = ((lane & 32) ? sB[0] : cB[0]) * ((lane & 16) ? sB[1] : cB[1]);
    fB *= ((lane & 8) ? sB[2] : cB[2]);
    fB *= ((lane & 4) ? sB[3] : cB[3]);
    fB *= ((lane & 2) ? sB[4] : cB[4]);
    fB *= ((lane & 1) ? sB[5] : cB[5]);
    Sr[0].x = fA * (cA[6]*cA[7]); Sr[0].y = fB * (cB[6]*cB[7]);
    Sr[1].x = fA * (cA[6]*sA[7]); Sr[1].y = fB * (cB[6]*sB[7]);
    Sr[2].x = fA * (sA[6]*cA[7]); Sr[2].y = fB * (sB[6]*cB[7]);
    Sr[3].x = fA * (sA[6]*sA[7]); Sr[3].y = fB * (sB[6]*sB[7]);
    Si[0] = sp(0.0f); Si[1] = sp(0.0f); Si[2] = sp(0.0f); Si[3] = sp(0.0f);
  }

  // ---- fused circuit: F0, per block F1..F7 (+F8' into next block), F8 ----
  crossg<32, 0>(Sr, Si, G, lane, a32);
  for (int b = 0; b < 5; ++b) {
    const float* base = G + 8 + b * 112;
    crossg<16, 32>(Sr, Si, base +  0, lane, a32);
    crossg<8, 16> (Sr, Si, base + 16, lane, a32);
    crossg<4, 8>  (Sr, Si, base + 32, lane, a32);
    crossg<2, 4>  (Sr, Si, base + 48, lane, a32);
    crossg<1, 2>  (Sr, Si, base + 64, lane, a32);
    f6(Sr, Si, base + 80, lane);
    f7(Sr, Si, base + 96);
    if (b < 4) f8p(Sr, Si, G + 568 + b * 16, lane, a32);
  }
  f8(Sr, Si, G + 632, lane, a32);

  // ---- measurements with immediate FC fold ----
  const bool selA = lane < 32;
  const int c = lane & 31;
  float accO = fcb[c];
  accO = fcStage(Sr, Si, lane, a32, sgv, FCW2 + (0 * 32 + c) * 8, selA, accO);
  hstepP<1>(Sr, Si, sp(sgv[0]), a32);
  hstepP<2>(Sr, Si, sp(sgv[1]), a32);
  hstepP<4>(Sr, Si, sp(sgv[2]), a32);
  hstepP<8>(Sr, Si, sp(sgv[3]), a32);
  hstepP<16>(Sr, Si, sp(sgv[4]), a32);
  hstepP<32>(Sr, Si, sp(sgv[5]), a32);
  h_intraP(Sr, Si);
  accO = fcStage(Sr, Si, lane, a32, sgv, FCW2 + (1 * 32 + c) * 8, selA, accO);
  phaseY(Sr, Si, lane);
  hstepP<1>(Sr, Si, sp(sgv[0]), a32);
  hstepP<2>(Sr, Si, sp(sgv[1]), a32);
  hstepP<4>(Sr, Si, sp(sgv[2]), a32);
  hstepP<8>(Sr, Si, sp(sgv[3]), a32);
  hstepP<16>(Sr, Si, sp(sgv[4]), a32);
  hstepP<32>(Sr, Si, sp(sgv[5]), a32);
  h_intraP(Sr, Si);
  accO = fcStage(Sr, Si, lane, a32, sgv, FCW2 + (2 * 32 + c) * 8, selA, accO);

  // out[b, c, h, w]; lanes 0-31 -> p0, lanes 32-63 -> p1.
  int p = selA ? p0 : (p0 + 1);
  out[(p >> 12) * 131072 + c * 4096 + (p & 4095)] = accO;
}

extern "C" void kernel_launch(void* const* d_in, const int* in_sizes, int n_in,
                              void* d_out, int out_size, void* d_ws, size_t ws_size,
                              hipStream_t stream) {
  const float* x      = (const float*)d_in[0];
  const float* conv_w = (const float*)d_in[1];
  const float* conv_b = (const float*)d_in[2];
  const float* u3p    = (const float*)d_in[3];
  const float* cu3p   = (const float*)d_in[4];
  const float* fcw    = (const float*)d_in[5];
  const float* fcb    = (const float*)d_in[6];
  float* out = (float*)d_out;

  float* ws   = (float*)d_ws;
  float* G    = ws;          // 640 (fused gate matrices)
  float* FCW2 = ws + 640;    // 768 (stage-major, pre-scaled)

  prep_kernel<<<1, 128, 0, stream>>>(u3p, cu3p, fcw, G, FCW2);
  qconv_kernel<<<2048, 256, 0, stream>>>(x, conv_w, conv_b, G, FCW2, fcb, out);
}

// Round 6
// 126.767 us; speedup vs baseline: 2.8703x; 1.0907x over previous
//
#include <hip/hip_runtime.h>

#define N_PIX 16384   // 4 * 64 * 64

typedef float v2f __attribute__((ext_vector_type(2)));

// ---------------------------------------------------------------------------
// Cross-lane butterfly helpers: DPP for xor 1/2/8 (VALU pipe), ds_swizzle for
// xor 4/16, ds_bpermute for xor 32.
// ---------------------------------------------------------------------------
template<int C>
__device__ __forceinline__ float dppmov(float x) {
  return __int_as_float(__builtin_amdgcn_update_dpp(0, __float_as_int(x), C, 0xF, 0xF, true));
}
template<int IMM>
__device__ __forceinline__ float dswz(float x) {
  return __int_as_float(__builtin_amdgcn_ds_swizzle(__float_as_int(x), IMM));
}
__device__ __forceinline__ float bperm(float x, int a32) {
  return __int_as_float(__builtin_amdgcn_ds_bpermute(a32, __float_as_int(x)));
}
template<int M>
__device__ __forceinline__ float bfly(float x, int a32) {
  if constexpr (M == 1)       return dppmov<0xB1>(x);
  else if constexpr (M == 2)  return dppmov<0x4E>(x);
  else if constexpr (M == 8)  return dppmov<0x128>(x);
  else if constexpr (M == 4)  return dswz<0x101F>(x);
  else if constexpr (M == 16) return dswz<0x401F>(x);
  else                        return bperm(x, a32);
}
template<int M>
__device__ __forceinline__ v2f bfly2(v2f v, int a32) {
  v2f o; o.x = bfly<M>(v.x, a32); o.y = bfly<M>(v.y, a32); return o;
}
__device__ __forceinline__ float rdlane(float x, int l) {
  return __int_as_float(__builtin_amdgcn_readlane(__float_as_int(x), l));
}
__device__ __forceinline__ float rdfirst(float x) {
  return __int_as_float(__builtin_amdgcn_readfirstlane(__float_as_int(x)));
}
__device__ __forceinline__ v2f sp(float s) { v2f v; v.x = s; v.y = s; return v; }
__device__ __forceinline__ v2f vfma(v2f a, v2f b, v2f c) {
  return __builtin_elementwise_fma(a, b, c);
}

// ---------------------------------------------------------------------------
// 4 pixels per wave: two packed v2f states P (pixels 0,1) and Q (pixels 2,3).
// amp index i = lane*4 + r. wire w<=5 <-> lane mask 32>>w; wire6 = r bit1;
// wire7 = r bit0. Gate coefficients computed once, applied to both chains —
// two independent ds-latency chains per wave (ILP) + amortized selects.
// ---------------------------------------------------------------------------
template<int M, int CM>
__device__ __forceinline__ void crossg4(v2f Pr[4], v2f Pi[4],
    v2f Qr[4], v2f Qi[4], const float* __restrict__ g, int lane, int a32) {
  const bool hi = (lane & M) != 0;
  float fr, fi, gr, gi;
  if constexpr (CM == 0) {
    fr = hi ? g[6] : g[0]; fi = hi ? g[7] : g[1];
    gr = hi ? g[4] : g[2]; gi = hi ? g[5] : g[3];
  } else {
    const bool ct = (lane & CM) != 0;
    float f0r = hi ? g[6]  : g[0],  f0i = hi ? g[7]  : g[1];
    float g0r = hi ? g[4]  : g[2],  g0i = hi ? g[5]  : g[3];
    float f1r = hi ? g[14] : g[8],  f1i = hi ? g[15] : g[9];
    float g1r = hi ? g[12] : g[10], g1i = hi ? g[13] : g[11];
    fr = ct ? f1r : f0r; fi = ct ? f1i : f0i;
    gr = ct ? g1r : g0r; gi = ct ? g1i : g0i;
  }
  v2f vfr = sp(fr), vfi = sp(fi), vgr = sp(gr), vgi = sp(gi);
  v2f vfiN = sp(-fi), vgiN = sp(-gi);
#pragma unroll
  for (int r = 0; r < 4; ++r) {
    v2f pPR = bfly2<M>(Pr[r], a32);
    v2f pPI = bfly2<M>(Pi[r], a32);
    v2f pQR = bfly2<M>(Qr[r], a32);
    v2f pQI = bfly2<M>(Qi[r], a32);
    v2f nPR = vfma(vgiN, pPI, vfma(vgr, pPR, vfma(vfiN, Pi[r], vfr * Pr[r])));
    v2f nPI = vfma(vgi,  pPR, vfma(vgr, pPI, vfma(vfi,  Pr[r], vfr * Pi[r])));
    v2f nQR = vfma(vgiN, pQI, vfma(vgr, pQR, vfma(vfiN, Qi[r], vfr * Qr[r])));
    v2f nQI = vfma(vgi,  pQR, vfma(vgr, pQI, vfma(vfi,  Qr[r], vfr * Qi[r])));
    Pr[r] = nPR; Pi[r] = nPI; Qr[r] = nQR; Qi[r] = nQI;
  }
}

__device__ __forceinline__ void mixP(v2f& x0r, v2f& x0i, v2f& x1r, v2f& x1i,
    float m0r, float m0i, float m1r, float m1i,
    float m2r, float m2i, float m3r, float m3i) {
  v2f n0r = vfma(sp(-m1i), x1i, vfma(sp(m1r), x1r, vfma(sp(-m0i), x0i, sp(m0r) * x0r)));
  v2f n0i = vfma(sp( m1i), x1r, vfma(sp(m1r), x1i, vfma(sp( m0i), x0r, sp(m0r) * x0i)));
  v2f n1r = vfma(sp(-m3i), x1i, vfma(sp(m3r), x1r, vfma(sp(-m2i), x0i, sp(m2r) * x0r)));
  v2f n1i = vfma(sp( m3i), x1r, vfma(sp(m3r), x1i, vfma(sp( m2i), x0r, sp(m2r) * x0i)));
  x0r = n0r; x0i = n0i; x1r = n1r; x1i = n1i;
}

// F6: target reg bit1, ctrl lane bit0 selects M0/M1 (select shared by P,Q).
__device__ __forceinline__ void f6q(v2f Pr[4], v2f Pi[4], v2f Qr[4], v2f Qi[4],
    const float* __restrict__ g, int lane) {
  const bool ct = (lane & 1) != 0;
  float m[8];
#pragma unroll
  for (int j = 0; j < 8; ++j) m[j] = ct ? g[8 + j] : g[j];
  mixP(Pr[0], Pi[0], Pr[2], Pi[2], m[0],m[1],m[2],m[3],m[4],m[5],m[6],m[7]);
  mixP(Pr[1], Pi[1], Pr[3], Pi[3], m[0],m[1],m[2],m[3],m[4],m[5],m[6],m[7]);
  mixP(Qr[0], Qi[0], Qr[2], Qi[2], m[0],m[1],m[2],m[3],m[4],m[5],m[6],m[7]);
  mixP(Qr[1], Qi[1], Qr[3], Qi[3], m[0],m[1],m[2],m[3],m[4],m[5],m[6],m[7]);
}

// F7: target reg bit0; pair (0,1) uses M0, pair (2,3) uses M1.
__device__ __forceinline__ void f7q(v2f Pr[4], v2f Pi[4], v2f Qr[4], v2f Qi[4],
    const float* __restrict__ g) {
  mixP(Pr[0], Pi[0], Pr[1], Pi[1], g[0],g[1],g[2],g[3],g[4],g[5],g[6],g[7]);
  mixP(Pr[2], Pi[2], Pr[3], Pi[3], g[8],g[9],g[10],g[11],g[12],g[13],g[14],g[15]);
  mixP(Qr[0], Qi[0], Qr[1], Qi[1], g[0],g[1],g[2],g[3],g[4],g[5],g[6],g[7]);
  mixP(Qr[2], Qi[2], Qr[3], Qi[3], g[8],g[9],g[10],g[11],g[12],g[13],g[14],g[15]);
}

// F8': target lane mask 32; even regs use M0, odd regs use M1.
__device__ __forceinline__ void f8pq(v2f Pr[4], v2f Pi[4], v2f Qr[4], v2f Qi[4],
    const float* __restrict__ g, int lane, int a32) {
  const bool hi = (lane & 32) != 0;
  float fr[2], fi[2], gr[2], gi[2];
  fr[0] = hi ? g[6]  : g[0];  fi[0] = hi ? g[7]  : g[1];
  gr[0] = hi ? g[4]  : g[2];  gi[0] = hi ? g[5]  : g[3];
  fr[1] = hi ? g[14] : g[8];  fi[1] = hi ? g[15] : g[9];
  gr[1] = hi ? g[12] : g[10]; gi[1] = hi ? g[13] : g[11];
#pragma unroll
  for (int r = 0; r < 4; ++r) {
    const int m = r & 1;
    v2f pPR = bfly2<32>(Pr[r], a32), pPI = bfly2<32>(Pi[r], a32);
    v2f pQR = bfly2<32>(Qr[r], a32), pQI = bfly2<32>(Qi[r], a32);
    v2f nPR = vfma(sp(-gi[m]), pPI, vfma(sp(gr[m]), pPR, vfma(sp(-fi[m]), Pi[r], sp(fr[m]) * Pr[r])));
    v2f nPI = vfma(sp( gi[m]), pPR, vfma(sp(gr[m]), pPI, vfma(sp( fi[m]), Pr[r], sp(fr[m]) * Pi[r])));
    v2f nQR = vfma(sp(-gi[m]), pQI, vfma(sp(gr[m]), pQR, vfma(sp(-fi[m]), Qi[r], sp(fr[m]) * Qr[r])));
    v2f nQI = vfma(sp( gi[m]), pQR, vfma(sp(gr[m]), pQI, vfma(sp( fi[m]), Qr[r], sp(fr[m]) * Qi[r])));
    Pr[r] = nPR; Pi[r] = nPI; Qr[r] = nQR; Qi[r] = nQI;
  }
}

// F8 final: cu3(7->0): odd regs only, target mask 32.
__device__ __forceinline__ void f8q(v2f Pr[4], v2f Pi[4], v2f Qr[4], v2f Qi[4],
    const float* __restrict__ g, int lane, int a32) {
  const bool hi = (lane & 32) != 0;
  float fr = hi ? g[6] : g[0], fi = hi ? g[7] : g[1];
  float gr = hi ? g[4] : g[2], gi = hi ? g[5] : g[3];
#pragma unroll
  for (int rr = 0; rr < 2; ++rr) {
    const int r = 2 * rr + 1;
    v2f pPR = bfly2<32>(Pr[r], a32), pPI = bfly2<32>(Pi[r], a32);
    v2f pQR = bfly2<32>(Qr[r], a32), pQI = bfly2<32>(Qi[r], a32);
    v2f nPR = vfma(sp(-gi), pPI, vfma(sp(gr), pPR, vfma(sp(-fi), Pi[r], sp(fr) * Pr[r])));
    v2f nPI = vfma(sp( gi), pPR, vfma(sp(gr), pPI, vfma(sp( fi), Pr[r], sp(fr) * Pi[r])));
    v2f nQR = vfma(sp(-gi), pQI, vfma(sp(gr), pQR, vfma(sp(-fi), Qi[r], sp(fr) * Qr[r])));
    v2f nQI = vfma(sp( gi), pQR, vfma(sp(gr), pQI, vfma(sp( fi), Qr[r], sp(fr) * Qi[r])));
    Pr[r] = nPR; Pi[r] = nPI; Qr[r] = nQR; Qi[r] = nQI;
  }
}

template<int M>
__device__ __forceinline__ void hstep4(v2f Pr[4], v2f Pi[4], v2f Qr[4], v2f Qi[4],
    v2f sgn, int a32) {
#pragma unroll
  for (int r = 0; r < 4; ++r) {
    v2f pPR = bfly2<M>(Pr[r], a32), pPI = bfly2<M>(Pi[r], a32);
    v2f pQR = bfly2<M>(Qr[r], a32), pQI = bfly2<M>(Qi[r], a32);
    Pr[r] = vfma(sgn, Pr[r], pPR);
    Pi[r] = vfma(sgn, Pi[r], pPI);
    Qr[r] = vfma(sgn, Qr[r], pQR);
    Qi[r] = vfma(sgn, Qi[r], pQI);
  }
}
__device__ __forceinline__ void hp(v2f& a, v2f& b) { v2f t = a; a = t + b; b = t - b; }
__device__ __forceinline__ void h_intraP(v2f Sr[4], v2f Si[4]) {
  hp(Sr[0], Sr[2]); hp(Si[0], Si[2]); hp(Sr[1], Sr[3]); hp(Si[1], Si[3]);
  hp(Sr[0], Sr[1]); hp(Si[0], Si[1]); hp(Sr[2], Sr[3]); hp(Si[2], Si[3]);
}

__device__ __forceinline__ void phaseY(v2f Sr[4], v2f Si[4], int lane) {
  const int pl = __popc(lane);
#pragma unroll
  for (int r = 0; r < 4; ++r) {
    const int pcr = (r == 0) ? 0 : ((r == 3) ? 2 : 1);
    const int q = (pl + pcr) & 3;
    const bool b0 = (q & 1) != 0;
    const bool b1 = (q & 2) != 0;
    const float sR = b1 ? -1.0f : 1.0f;
    const float sI = (b0 != b1) ? -1.0f : 1.0f;
    v2f Rs = b0 ? Si[r] : Sr[r];
    v2f Is = b0 ? Sr[r] : Si[r];
    Sr[r] = sp(sR) * Rs;
    Si[r] = sp(sI) * Is;
  }
}

// <Z_w> for one packed pair -> mA/mB in SGPRs (via readlane).
__device__ __forceinline__ void measureP(const v2f Sr[4], const v2f Si[4],
    int lane, int a32, const float* sgv, float* mA, float* mB) {
  v2f P[4];
#pragma unroll
  for (int r = 0; r < 4; ++r) P[r] = vfma(Si[r], Si[r], Sr[r] * Sr[r]);
  v2f t01 = P[0] + P[1], t23 = P[2] + P[3];
  v2f a  = t01 + t23;
  v2f d1 = t01 - t23;                       // wire 6
  v2f d0 = (P[0] - P[1]) + (P[2] - P[3]);   // wire 7
  a = vfma(sp(sgv[0]), a, bfly2<1>(a, a32));
  a = vfma(sp(sgv[1]), a, bfly2<2>(a, a32));
  a = vfma(sp(sgv[2]), a, bfly2<4>(a, a32));
  a = vfma(sp(sgv[3]), a, bfly2<8>(a, a32));
  a = vfma(sp(sgv[4]), a, bfly2<16>(a, a32));
  a = vfma(sp(sgv[5]), a, bfly2<32>(a, a32));
  mA[0] = rdlane(a.x, 32); mA[1] = rdlane(a.x, 16); mA[2] = rdlane(a.x, 8);
  mA[3] = rdlane(a.x, 4);  mA[4] = rdlane(a.x, 2);  mA[5] = rdlane(a.x, 1);
  mB[0] = rdlane(a.y, 32); mB[1] = rdlane(a.y, 16); mB[2] = rdlane(a.y, 8);
  mB[3] = rdlane(a.y, 4);  mB[4] = rdlane(a.y, 2);  mB[5] = rdlane(a.y, 1);
  d1 = d1 + bfly2<1>(d1, a32);  d0 = d0 + bfly2<1>(d0, a32);
  d1 = d1 + bfly2<2>(d1, a32);  d0 = d0 + bfly2<2>(d0, a32);
  d1 = d1 + bfly2<4>(d1, a32);  d0 = d0 + bfly2<4>(d0, a32);
  d1 = d1 + bfly2<8>(d1, a32);  d0 = d0 + bfly2<8>(d0, a32);
  d1 = d1 + bfly2<16>(d1, a32); d0 = d0 + bfly2<16>(d0, a32);
  d1 = d1 + bfly2<32>(d1, a32); d0 = d0 + bfly2<32>(d0, a32);
  mA[6] = rdfirst(d1.x); mA[7] = rdfirst(d0.x);
  mB[6] = rdfirst(d1.y); mB[7] = rdfirst(d0.y);
}

// One measurement stage for all 4 pixels folded into the two FC accumulators.
// Per-pixel partials accumulate as SGPR*VGPR fmas; single cndmask at the end.
__device__ __forceinline__ void fcStage4(const v2f Pr[4], const v2f Pi[4],
    const v2f Qr[4], const v2f Qi[4], int lane, int a32, const float* sgv,
    const float* __restrict__ wrow, bool selA, float& acc01, float& acc23) {
  float mA[8], mB[8], mC[8], mD[8];
  measureP(Pr, Pi, lane, a32, sgv, mA, mB);
  measureP(Qr, Qi, lane, a32, sgv, mC, mD);
  const float4* w4 = reinterpret_cast<const float4*>(wrow);
  float4 w0 = w4[0], w1 = w4[1];
  float wj[8] = {w0.x, w0.y, w0.z, w0.w, w1.x, w1.y, w1.z, w1.w};
  float aA = 0.0f, aB = 0.0f, aC = 0.0f, aD = 0.0f;
#pragma unroll
  for (int j = 0; j < 8; ++j) {
    aA = fmaf(mA[j], wj[j], aA);
    aB = fmaf(mB[j], wj[j], aB);
    aC = fmaf(mC[j], wj[j], aC);
    aD = fmaf(mD[j], wj[j], aD);
  }
  acc01 += selA ? aA : aB;
  acc23 += selA ? aC : aD;
}

// ---------------------------------------------------------------------------
// Conv pass: angle for pixel (ppair + lane>>5), channel (lane>>2)&7, partial
// over 4 input channels (lane&3), DPP xor1/xor2 reduced.
// ---------------------------------------------------------------------------
__device__ __forceinline__ float convPass(const float* __restrict__ x,
    const float* __restrict__ cw, const float* __restrict__ cb,
    int lane, int ppair) {
  const int icg = lane & 3;
  const int oc  = (lane >> 2) & 7;
  const int px  = lane >> 5;
  const int p   = ppair + px;
  const int b   = p >> 12;
  const int hh  = (p >> 6) & 63;
  const int wim = p & 63;
  float acc = 0.0f;
#pragma unroll 2
  for (int il = 0; il < 4; ++il) {
    const int ic = icg * 4 + il;
    const float* wp = cw + (oc * 16 + ic) * 9;
    const float* xp = x + (b * 16 + ic) * 4096;
#pragma unroll
    for (int kh = 0; kh < 3; ++kh) {
      int ih = hh + kh - 1;
      bool rok = (unsigned)ih < 64u;
      int ihc = rok ? ih : 0;
#pragma unroll
      for (int kw = 0; kw < 3; ++kw) {
        int iw = wim + kw - 1;
        bool ok = rok && ((unsigned)iw < 64u);
        int iwc = ((unsigned)iw < 64u) ? iw : 0;
        float xv = xp[ihc * 64 + iwc];
        acc = fmaf(ok ? xv : 0.0f, wp[kh * 3 + kw], acc);
      }
    }
  }
  acc += bfly<1>(acc, 0);
  acc += bfly<2>(acc, 0);
  return acc + cb[oc];
}

// Build RY-product state for one packed pair from the 16 broadcast angles.
__device__ __forceinline__ void initState(float angAcc, int lane,
    v2f Sr[4], v2f Si[4]) {
  float cA[8], sA[8], cB[8], sB[8];
#pragma unroll
  for (int w = 0; w < 8; ++w) {
    float aa = 0.5f * rdlane(angAcc, w * 4);
    float ab = 0.5f * rdlane(angAcc, 32 + w * 4);
    __sincosf(aa, &sA[w], &cA[w]);
    __sincosf(ab, &sB[w], &cB[w]);
  }
  float fA = ((lane & 32) ? sA[0] : cA[0]) * ((lane & 16) ? sA[1] : cA[1]);
  fA *= ((lane & 8) ? sA[2] : cA[2]);
  fA *= ((lane & 4) ? sA[3] : cA[3]);
  fA *= ((lane & 2) ? sA[4] : cA[4]);
  fA *= ((lane & 1) ? sA[5] : cA[5]);
  float fB = ((lane & 32) ? sB[0] : cB[0]) * ((lane & 16) ? sB[1] : cB[1]);
  fB *= ((lane & 8) ? sB[2] : cB[2]);
  fB *= ((lane & 4) ? sB[3] : cB[3]);
  fB *= ((lane & 2) ? sB[4] : cB[4]);
  fB *= ((lane & 1) ? sB[5] : cB[5]);
  Sr[0].x = fA * (cA[6]*cA[7]); Sr[0].y = fB * (cB[6]*cB[7]);
  Sr[1].x = fA * (cA[6]*sA[7]); Sr[1].y = fB * (cB[6]*sB[7]);
  Sr[2].x = fA * (sA[6]*cA[7]); Sr[2].y = fB * (sB[6]*cB[7]);
  Sr[3].x = fA * (sA[6]*sA[7]); Sr[3].y = fB * (sB[6]*sB[7]);
  Si[0] = sp(0.0f); Si[1] = sp(0.0f); Si[2] = sp(0.0f); Si[3] = sp(0.0f);
}

// ---------------------------------------------------------------------------
// Prep helpers.
// ---------------------------------------------------------------------------
__device__ __forceinline__ void mm2(const float* A, const float* B, float* D) {
  D[0] = A[0]*B[0] - A[1]*B[1] + A[2]*B[4] - A[3]*B[5];
  D[1] = A[0]*B[1] + A[1]*B[0] + A[2]*B[5] + A[3]*B[4];
  D[2] = A[0]*B[2] - A[1]*B[3] + A[2]*B[6] - A[3]*B[7];
  D[3] = A[0]*B[3] + A[1]*B[2] + A[2]*B[7] + A[3]*B[6];
  D[4] = A[4]*B[0] - A[5]*B[1] + A[6]*B[4] - A[7]*B[5];
  D[5] = A[4]*B[1] + A[5]*B[0] + A[6]*B[5] + A[7]*B[4];
  D[6] = A[4]*B[2] - A[5]*B[3] + A[6]*B[6] - A[7]*B[7];
  D[7] = A[4]*B[3] + A[5]*B[2] + A[6]*B[7] + A[7]*B[6];
}
__device__ __forceinline__ void u3fill(const float* src, float* o) {
  float th = src[0], ph = src[1], lam = src[2];
  float c = cosf(0.5f * th), s = sinf(0.5f * th);
  float cl = cosf(lam), sl = sinf(lam);
  float cp = cosf(ph), spv = sinf(ph);
  float cpl = cosf(ph + lam), spl = sinf(ph + lam);
  o[0] = c;        o[1] = 0.0f;
  o[2] = -cl * s;  o[3] = -sl * s;
  o[4] = cp * s;   o[5] = spv * s;
  o[6] = cpl * c;  o[7] = spl * c;
}

__global__ __launch_bounds__(128) void prep_kernel(
    const float* __restrict__ u3p, const float* __restrict__ cu3p,
    const float* __restrict__ fcw, float* __restrict__ G,
    float* __restrict__ FCW2) {
  __shared__ float Us[40][8];
  __shared__ float Cs[40][8];
  int t = threadIdx.x;
  if (t < 40) u3fill(u3p + t * 3, Us[t]);
  if (t >= 64 && t < 104) u3fill(cu3p + (t - 64) * 3, Cs[t - 64]);
  __syncthreads();
  if (t == 0) {
#pragma unroll
    for (int j = 0; j < 8; ++j) G[j] = Us[0][j];
  } else if (t < 36) {
    int j = t - 1, b = j / 7, k = j % 7;
    float* dst = G + 8 + b * 112 + k * 16;
    const float* U = Us[b * 8 + k + 1];
    const float* C = Cs[b * 8 + k];
#pragma unroll
    for (int q = 0; q < 8; ++q) dst[q] = U[q];
    mm2(C, U, dst + 8);
  } else if (t < 40) {
    int b = t - 36;
    float* dst = G + 568 + b * 16;
    const float* U = Us[(b + 1) * 8];
    const float* C = Cs[b * 8 + 7];
#pragma unroll
    for (int q = 0; q < 8; ++q) dst[q] = U[q];
    mm2(U, C, dst + 8);
  } else if (t == 40) {
#pragma unroll
    for (int j = 0; j < 8; ++j) G[632 + j] = Cs[39][j];
  }
  for (int i = t; i < 768; i += 128) {
    int s = i >> 8, cc = (i >> 3) & 31, wv = i & 7;
    float sc = (s == 0) ? 1.0f : ((s == 1) ? (1.0f / 256.0f) : (1.0f / 65536.0f));
    FCW2[i] = fcw[cc * 24 + s * 8 + wv] * sc;
  }
}

// ---------------------------------------------------------------------------
// Fused conv + quantum simulator: 4 pixels per wave64 (two packed v2f chains).
// Plain __launch_bounds__(256): any VGPR cap risks round-4-style spills.
// ---------------------------------------------------------------------------
__global__ __launch_bounds__(256) void qconv_kernel(
    const float* __restrict__ x, const float* __restrict__ cw,
    const float* __restrict__ cb, const float* __restrict__ G,
    const float* __restrict__ FCW2, const float* __restrict__ fcb,
    float* __restrict__ out) {
  const int lane = threadIdx.x & 63;
  const int a32 = ((lane ^ 32) << 2);
  const int wid = __builtin_amdgcn_readfirstlane(
      (int)((blockIdx.x * blockDim.x + threadIdx.x) >> 6));
  const int p0 = wid * 4;

  float sgv[6];
#pragma unroll
  for (int k = 0; k < 6; ++k) sgv[k] = (lane & (1 << k)) ? -1.0f : 1.0f;

  v2f Pr[4], Pi[4], Qr[4], Qi[4];
  {
    float ang0 = convPass(x, cw, cb, lane, p0);
    initState(ang0, lane, Pr, Pi);
  }
  {
    float ang1 = convPass(x, cw, cb, lane, p0 + 2);
    initState(ang1, lane, Qr, Qi);
  }

  // ---- fused circuit ----
  crossg4<32, 0>(Pr, Pi, Qr, Qi, G, lane, a32);
  for (int b = 0; b < 5; ++b) {
    const float* base = G + 8 + b * 112;
    crossg4<16, 32>(Pr, Pi, Qr, Qi, base +  0, lane, a32);
    crossg4<8, 16> (Pr, Pi, Qr, Qi, base + 16, lane, a32);
    crossg4<4, 8>  (Pr, Pi, Qr, Qi, base + 32, lane, a32);
    crossg4<2, 4>  (Pr, Pi, Qr, Qi, base + 48, lane, a32);
    crossg4<1, 2>  (Pr, Pi, Qr, Qi, base + 64, lane, a32);
    f6q(Pr, Pi, Qr, Qi, base + 80, lane);
    f7q(Pr, Pi, Qr, Qi, base + 96);
    if (b < 4) f8pq(Pr, Pi, Qr, Qi, G + 568 + b * 16, lane, a32);
  }
  f8q(Pr, Pi, Qr, Qi, G + 632, lane, a32);

  // ---- measurements with immediate FC fold ----
  const bool selA = lane < 32;
  const int c = lane & 31;
  float acc01 = fcb[c], acc23 = acc01;
  fcStage4(Pr, Pi, Qr, Qi, lane, a32, sgv, FCW2 + (0 * 32 + c) * 8, selA, acc01, acc23);
  {
    v2f s0 = sp(sgv[0]), s1 = sp(sgv[1]), s2 = sp(sgv[2]);
    v2f s3 = sp(sgv[3]), s4 = sp(sgv[4]), s5 = sp(sgv[5]);
    hstep4<1>(Pr, Pi, Qr, Qi, s0, a32);
    hstep4<2>(Pr, Pi, Qr, Qi, s1, a32);
    hstep4<4>(Pr, Pi, Qr, Qi, s2, a32);
    hstep4<8>(Pr, Pi, Qr, Qi, s3, a32);
    hstep4<16>(Pr, Pi, Qr, Qi, s4, a32);
    hstep4<32>(Pr, Pi, Qr, Qi, s5, a32);
  }
  h_intraP(Pr, Pi); h_intraP(Qr, Qi);
  fcStage4(Pr, Pi, Qr, Qi, lane, a32, sgv, FCW2 + (1 * 32 + c) * 8, selA, acc01, acc23);
  phaseY(Pr, Pi, lane); phaseY(Qr, Qi, lane);
  {
    v2f s0 = sp(sgv[0]), s1 = sp(sgv[1]), s2 = sp(sgv[2]);
    v2f s3 = sp(sgv[3]), s4 = sp(sgv[4]), s5 = sp(sgv[5]);
    hstep4<1>(Pr, Pi, Qr, Qi, s0, a32);
    hstep4<2>(Pr, Pi, Qr, Qi, s1, a32);
    hstep4<4>(Pr, Pi, Qr, Qi, s2, a32);
    hstep4<8>(Pr, Pi, Qr, Qi, s3, a32);
    hstep4<16>(Pr, Pi, Qr, Qi, s4, a32);
    hstep4<32>(Pr, Pi, Qr, Qi, s5, a32);
  }
  h_intraP(Pr, Pi); h_intraP(Qr, Qi);
  fcStage4(Pr, Pi, Qr, Qi, lane, a32, sgv, FCW2 + (2 * 32 + c) * 8, selA, acc01, acc23);

  // out[b, c, h, w]; pair P -> pixels p0/p0+1, pair Q -> p0+2/p0+3.
  int pA = selA ? p0 : (p0 + 1);
  int base = (pA >> 12) * 131072 + c * 4096;
  out[base + (pA & 4095)] = acc01;
  out[base + ((pA + 2) & 4095)] = acc23;
}

extern "C" void kernel_launch(void* const* d_in, const int* in_sizes, int n_in,
                              void* d_out, int out_size, void* d_ws, size_t ws_size,
                              hipStream_t stream) {
  const float* x      = (const float*)d_in[0];
  const float* conv_w = (const float*)d_in[1];
  const float* conv_b = (const float*)d_in[2];
  const float* u3p    = (const float*)d_in[3];
  const float* cu3p   = (const float*)d_in[4];
  const float* fcw    = (const float*)d_in[5];
  const float* fcb    = (const float*)d_in[6];
  float* out = (float*)d_out;

  float* ws   = (float*)d_ws;
  float* G    = ws;          // 640 (fused gate matrices)
  float* FCW2 = ws + 640;    // 768 (stage-major, pre-scaled)

  prep_kernel<<<1, 128, 0, stream>>>(u3p, cu3p, fcw, G, FCW2);
  qconv_kernel<<<1024, 256, 0, stream>>>(x, conv_w, conv_b, G, FCW2, fcb, out);
}

// Round 7
// 112.634 us; speedup vs baseline: 3.2305x; 1.1255x over previous
//
#include <hip/hip_runtime.h>

typedef float v2f __attribute__((ext_vector_type(2)));

// ---------------------------------------------------------------------------
// Cross-lane helpers. New layout only needs masks 1,2,8 (DPP, VALU pipe) and
// 4 (ds_swizzle); ds_bpermute only for the one-time angle gather.
// ---------------------------------------------------------------------------
template<int C>
__device__ __forceinline__ float dppmov(float x) {
  return __int_as_float(__builtin_amdgcn_update_dpp(0, __float_as_int(x), C, 0xF, 0xF, true));
}
template<int IMM>
__device__ __forceinline__ float dswz(float x) {
  return __int_as_float(__builtin_amdgcn_ds_swizzle(__float_as_int(x), IMM));
}
__device__ __forceinline__ float bperm(float x, int a) {
  return __int_as_float(__builtin_amdgcn_ds_bpermute(a, __float_as_int(x)));
}
template<int M>
__device__ __forceinline__ float bfly(float x) {
  if constexpr (M == 1)      return dppmov<0xB1>(x);   // quad_perm [1,0,3,2]
  else if constexpr (M == 2) return dppmov<0x4E>(x);   // quad_perm [2,3,0,1]
  else if constexpr (M == 8) return dppmov<0x128>(x);  // row_ror:8 == xor8 in row
  else                       return dswz<0x101F>(x);   // M==4: bit-mode xor4
}
template<int M>
__device__ __forceinline__ v2f bfly2(v2f v) {
  v2f o; o.x = bfly<M>(v.x); o.y = bfly<M>(v.y); return o;
}
__device__ __forceinline__ v2f sp(float s) { v2f v; v.x = s; v.y = s; return v; }
__device__ __forceinline__ v2f vfma(v2f a, v2f b, v2f c) {
  return __builtin_elementwise_fma(a, b, c);
}

// ---------------------------------------------------------------------------
// Layout: 8 pixels/wave. Lane-group g = lane>>4 (16 lanes) holds the packed
// pixel pair (p0+2g, p0+2g+1) in v2f (.x, .y). Amp i = q*16 + r, q = lane&15,
// r = reg 0..15. Wire w<=3 <-> q bit (3-w) (masks 8,4,2,1); wires 4..7 <-> r
// bits 3..0 (intra-lane, shuffle-free).
// ---------------------------------------------------------------------------
template<int M, int CM>
__device__ __forceinline__ void crossG(v2f Sr[16], v2f Si[16],
    const float* __restrict__ g, int lane) {
  const bool hi = (lane & M) != 0;
  float fr, fi, gr, gi;
  if constexpr (CM == 0) {
    fr = hi ? g[6] : g[0]; fi = hi ? g[7] : g[1];
    gr = hi ? g[4] : g[2]; gi = hi ? g[5] : g[3];
  } else {
    const bool ct = (lane & CM) != 0;
    float f0r = hi ? g[6]  : g[0],  f0i = hi ? g[7]  : g[1];
    float g0r = hi ? g[4]  : g[2],  g0i = hi ? g[5]  : g[3];
    float f1r = hi ? g[14] : g[8],  f1i = hi ? g[15] : g[9];
    float g1r = hi ? g[12] : g[10], g1i = hi ? g[13] : g[11];
    fr = ct ? f1r : f0r; fi = ct ? f1i : f0i;
    gr = ct ? g1r : g0r; gi = ct ? g1i : g0i;
  }
  v2f vfr = sp(fr), vfi = sp(fi), vgr = sp(gr), vgi = sp(gi);
  v2f vfiN = sp(-fi), vgiN = sp(-gi);
#pragma unroll
  for (int r = 0; r < 16; ++r) {
    v2f pR = bfly2<M>(Sr[r]);
    v2f pI = bfly2<M>(Si[r]);
    v2f nR = vfma(vgiN, pI, vfma(vgr, pR, vfma(vfiN, Si[r], vfr * Sr[r])));
    v2f nI = vfma(vgi,  pR, vfma(vgr, pI, vfma(vfi,  Sr[r], vfr * Si[r])));
    Sr[r] = nR; Si[r] = nI;
  }
}

__device__ __forceinline__ void mixP(v2f& x0r, v2f& x0i, v2f& x1r, v2f& x1i,
    float m0r, float m0i, float m1r, float m1i,
    float m2r, float m2i, float m3r, float m3i) {
  v2f n0r = vfma(sp(-m1i), x1i, vfma(sp(m1r), x1r, vfma(sp(-m0i), x0i, sp(m0r) * x0r)));
  v2f n0i = vfma(sp( m1i), x1r, vfma(sp(m1r), x1i, vfma(sp( m0i), x0r, sp(m0r) * x0i)));
  v2f n1r = vfma(sp(-m3i), x1i, vfma(sp(m3r), x1r, vfma(sp(-m2i), x0i, sp(m2r) * x0r)));
  v2f n1i = vfma(sp( m3i), x1r, vfma(sp(m3r), x1i, vfma(sp( m2i), x0r, sp(m2r) * x0i)));
  x0r = n0r; x0i = n0i; x1r = n1r; x1i = n1i;
}

// F4: fused u3(w4)+cu3(3->4): ctrl lane bit0 (runtime), target r bit3.
__device__ __forceinline__ void f4N(v2f Sr[16], v2f Si[16],
    const float* __restrict__ g, int lane) {
  const bool ct = (lane & 1) != 0;
  float m[8];
#pragma unroll
  for (int jj = 0; jj < 8; ++jj) m[jj] = ct ? g[8 + jj] : g[jj];
#pragma unroll
  for (int r = 0; r < 8; ++r)
    mixP(Sr[r], Si[r], Sr[r + 8], Si[r + 8],
         m[0], m[1], m[2], m[3], m[4], m[5], m[6], m[7]);
}
// F5: ctrl r bit3 (compile-time), target r bit2.
__device__ __forceinline__ void f5N(v2f Sr[16], v2f Si[16],
    const float* __restrict__ g) {
#pragma unroll
  for (int r = 0; r < 4; ++r)
    mixP(Sr[r], Si[r], Sr[r + 4], Si[r + 4],
         g[0], g[1], g[2], g[3], g[4], g[5], g[6], g[7]);
#pragma unroll
  for (int r = 8; r < 12; ++r)
    mixP(Sr[r], Si[r], Sr[r + 4], Si[r + 4],
         g[8], g[9], g[10], g[11], g[12], g[13], g[14], g[15]);
}
// F6: ctrl r bit2, target r bit1.
__device__ __forceinline__ void f6N(v2f Sr[16], v2f Si[16],
    const float* __restrict__ g) {
#pragma unroll
  for (int t = 0; t < 4; ++t) {
    const int r0 = (t >> 1) * 8 + (t & 1);  // 0,1,8,9  (bit2 = 0 -> M0)
    mixP(Sr[r0], Si[r0], Sr[r0 + 2], Si[r0 + 2],
         g[0], g[1], g[2], g[3], g[4], g[5], g[6], g[7]);
    const int r1 = r0 + 4;                  // 4,5,12,13 (bit2 = 1 -> M1)
    mixP(Sr[r1], Si[r1], Sr[r1 + 2], Si[r1 + 2],
         g[8], g[9], g[10], g[11], g[12], g[13], g[14], g[15]);
  }
}
// F7: ctrl r bit1, target r bit0.
__device__ __forceinline__ void f7N(v2f Sr[16], v2f Si[16],
    const float* __restrict__ g) {
#pragma unroll
  for (int t = 0; t < 4; ++t) {
    const int r0 = t * 4;                   // 0,4,8,12 (bit1 = 0 -> M0)
    mixP(Sr[r0], Si[r0], Sr[r0 + 1], Si[r0 + 1],
         g[0], g[1], g[2], g[3], g[4], g[5], g[6], g[7]);
    const int r1 = r0 + 2;                  // 2,6,10,14 (bit1 = 1 -> M1)
    mixP(Sr[r1], Si[r1], Sr[r1 + 1], Si[r1 + 1],
         g[8], g[9], g[10], g[11], g[12], g[13], g[14], g[15]);
  }
}
// F8': fused cu3(7->0)+next u3(w0): ctrl r bit0 (compile-time), target mask 8.
__device__ __forceinline__ void f8pN(v2f Sr[16], v2f Si[16],
    const float* __restrict__ g, int lane) {
  const bool hi = (lane & 8) != 0;
  float fr[2], fi[2], gr[2], gi[2];
  fr[0] = hi ? g[6]  : g[0];  fi[0] = hi ? g[7]  : g[1];
  gr[0] = hi ? g[4]  : g[2];  gi[0] = hi ? g[5]  : g[3];
  fr[1] = hi ? g[14] : g[8];  fi[1] = hi ? g[15] : g[9];
  gr[1] = hi ? g[12] : g[10]; gi[1] = hi ? g[13] : g[11];
#pragma unroll
  for (int r = 0; r < 16; ++r) {
    const int m = r & 1;
    v2f pR = bfly2<8>(Sr[r]);
    v2f pI = bfly2<8>(Si[r]);
    v2f nR = vfma(sp(-gi[m]), pI, vfma(sp(gr[m]), pR, vfma(sp(-fi[m]), Si[r], sp(fr[m]) * Sr[r])));
    v2f nI = vfma(sp( gi[m]), pR, vfma(sp(gr[m]), pI, vfma(sp( fi[m]), Sr[r], sp(fr[m]) * Si[r])));
    Sr[r] = nR; Si[r] = nI;
  }
}
// F8 final standalone cu3(7->0): odd r only, target mask 8.
__device__ __forceinline__ void f8N(v2f Sr[16], v2f Si[16],
    const float* __restrict__ g, int lane) {
  const bool hi = (lane & 8) != 0;
  const float fr = hi ? g[6] : g[0], fi = hi ? g[7] : g[1];
  const float gr = hi ? g[4] : g[2], gi = hi ? g[5] : g[3];
#pragma unroll
  for (int r = 1; r < 16; r += 2) {
    v2f pR = bfly2<8>(Sr[r]);
    v2f pI = bfly2<8>(Si[r]);
    v2f nR = vfma(sp(-gi), pI, vfma(sp(gr), pR, vfma(sp(-fi), Si[r], sp(fr) * Sr[r])));
    v2f nI = vfma(sp( gi), pR, vfma(sp(gr), pI, vfma(sp( fi), Sr[r], sp(fr) * Si[r])));
    Sr[r] = nR; Si[r] = nI;
  }
}

// Unnormalized Hadamard on all 8 wires (scale folded into FC weights).
template<int M>
__device__ __forceinline__ void hstepN(v2f Sr[16], v2f Si[16], float sgn) {
  v2f s = sp(sgn);
#pragma unroll
  for (int r = 0; r < 16; ++r) {
    v2f pR = bfly2<M>(Sr[r]);
    v2f pI = bfly2<M>(Si[r]);
    Sr[r] = vfma(s, Sr[r], pR);
    Si[r] = vfma(s, Si[r], pI);
  }
}
__device__ __forceinline__ void hp(v2f& a, v2f& b) { v2f t = a; a = t + b; b = t - b; }
__device__ __forceinline__ void hintraN(v2f S[16]) {
  hp(S[0],S[8]);  hp(S[1],S[9]);  hp(S[2],S[10]); hp(S[3],S[11]);
  hp(S[4],S[12]); hp(S[5],S[13]); hp(S[6],S[14]); hp(S[7],S[15]);
  hp(S[0],S[4]);  hp(S[1],S[5]);  hp(S[2],S[6]);  hp(S[3],S[7]);
  hp(S[8],S[12]); hp(S[9],S[13]); hp(S[10],S[14]); hp(S[11],S[15]);
  hp(S[0],S[2]);  hp(S[1],S[3]);  hp(S[4],S[6]);  hp(S[5],S[7]);
  hp(S[8],S[10]); hp(S[9],S[11]); hp(S[12],S[14]); hp(S[13],S[15]);
  hp(S[0],S[1]);  hp(S[2],S[3]);  hp(S[4],S[5]);  hp(S[6],S[7]);
  hp(S[8],S[9]);  hp(S[10],S[11]); hp(S[12],S[13]); hp(S[14],S[15]);
}
__device__ __forceinline__ void hallN(v2f Sr[16], v2f Si[16], const float* sg) {
  hstepN<8>(Sr, Si, sg[0]);
  hstepN<4>(Sr, Si, sg[1]);
  hstepN<2>(Sr, Si, sg[2]);
  hstepN<1>(Sr, Si, sg[3]);
  hintraN(Sr); hintraN(Si);
}

// diag(1,-i) on every wire: amp i *= (-i)^popc(i), popc(i)=popc(q)+popc(r).
__device__ __forceinline__ void phaseYN(v2f Sr[16], v2f Si[16], int lane) {
  const int pl = __popc(lane & 15);
#pragma unroll
  for (int r = 0; r < 16; ++r) {
    const int qq = (pl + __popc(r)) & 3;
    const bool b0 = (qq & 1) != 0;
    const bool b1 = (qq & 2) != 0;
    const float sR = b1 ? -1.0f : 1.0f;
    const float sI = (b0 != b1) ? -1.0f : 1.0f;
    v2f Rs = b0 ? Si[r] : Sr[r];
    v2f Is = b0 ? Sr[r] : Si[r];
    Sr[r] = sp(sR) * Rs;
    Si[r] = sp(sI) * Is;
  }
}

// <Z_w> for the lane-group's packed pair: 8 pre-signed chains, 4-step
// butterfly sums -> all 8 marginals group-uniform in every lane (v2f).
__device__ __forceinline__ void measureN(const v2f Sr[16], const v2f Si[16],
    const float* sg, v2f m[8]) {
  v2f P[16];
#pragma unroll
  for (int r = 0; r < 16; ++r) P[r] = vfma(Si[r], Si[r], Sr[r] * Sr[r]);
  v2f t01[8], d7 = sp(0.0f);
#pragma unroll
  for (int jj = 0; jj < 8; ++jj) {
    t01[jj] = P[2 * jj] + P[2 * jj + 1];
    d7 = d7 + (P[2 * jj] - P[2 * jj + 1]);
  }
  v2f d6 = (t01[0] - t01[1]) + (t01[2] - t01[3]) + (t01[4] - t01[5]) + (t01[6] - t01[7]);
  v2f q0 = t01[0] + t01[1], q1 = t01[2] + t01[3];
  v2f q2 = t01[4] + t01[5], q3 = t01[6] + t01[7];
  v2f d5 = (q0 - q1) + (q2 - q3);
  v2f d4 = (q0 + q1) - (q2 + q3);
  v2f pa = (q0 + q1) + (q2 + q3);
  v2f c0 = sp(sg[0]) * pa, c1 = sp(sg[1]) * pa;
  v2f c2 = sp(sg[2]) * pa, c3 = sp(sg[3]) * pa;
  v2f c4 = d4, c5 = d5, c6 = d6, c7 = d7;
#define BSUM(M) \
  c0 = c0 + bfly2<M>(c0); c1 = c1 + bfly2<M>(c1); \
  c2 = c2 + bfly2<M>(c2); c3 = c3 + bfly2<M>(c3); \
  c4 = c4 + bfly2<M>(c4); c5 = c5 + bfly2<M>(c5); \
  c6 = c6 + bfly2<M>(c6); c7 = c7 + bfly2<M>(c7);
  BSUM(1) BSUM(2) BSUM(4) BSUM(8)
#undef BSUM
  m[0] = c0; m[1] = c1; m[2] = c2; m[3] = c3;
  m[4] = c4; m[5] = c5; m[6] = c6; m[7] = c7;
}

// FC fold: lane handles pixel (.x/.y by q bit3) and channels 4*(q&7)+k.
__device__ __forceinline__ void fcN(const v2f m[8],
    const float* __restrict__ wbase, bool isB, int j, float acc[4]) {
  float mm[8];
#pragma unroll
  for (int w = 0; w < 8; ++w) mm[w] = isB ? m[w].y : m[w].x;
#pragma unroll
  for (int k = 0; k < 4; ++k) {
    const float4* w4 = reinterpret_cast<const float4*>(wbase + (4 * j + k) * 8);
    float4 a = w4[0], b = w4[1];
    float s = acc[k];
    s = fmaf(mm[0], a.x, s); s = fmaf(mm[1], a.y, s);
    s = fmaf(mm[2], a.z, s); s = fmaf(mm[3], a.w, s);
    s = fmaf(mm[4], b.x, s); s = fmaf(mm[5], b.y, s);
    s = fmaf(mm[6], b.z, s); s = fmaf(mm[7], b.w, s);
    acc[k] = s;
  }
}

// ---------------------------------------------------------------------------
// Prep (unchanged G table from round 3; same fusion algebra, new mask roles).
// ---------------------------------------------------------------------------
__device__ __forceinline__ void mm2(const float* A, const float* B, float* D) {
  D[0] = A[0]*B[0] - A[1]*B[1] + A[2]*B[4] - A[3]*B[5];
  D[1] = A[0]*B[1] + A[1]*B[0] + A[2]*B[5] + A[3]*B[4];
  D[2] = A[0]*B[2] - A[1]*B[3] + A[2]*B[6] - A[3]*B[7];
  D[3] = A[0]*B[3] + A[1]*B[2] + A[2]*B[7] + A[3]*B[6];
  D[4] = A[4]*B[0] - A[5]*B[1] + A[6]*B[4] - A[7]*B[5];
  D[5] = A[4]*B[1] + A[5]*B[0] + A[6]*B[5] + A[7]*B[4];
  D[6] = A[4]*B[2] - A[5]*B[3] + A[6]*B[6] - A[7]*B[7];
  D[7] = A[4]*B[3] + A[5]*B[2] + A[6]*B[7] + A[7]*B[6];
}
__device__ __forceinline__ void u3fill(const float* src, float* o) {
  float th = src[0], ph = src[1], lam = src[2];
  float c = cosf(0.5f * th), s = sinf(0.5f * th);
  float cl = cosf(lam), sl = sinf(lam);
  float cp = cosf(ph), spv = sinf(ph);
  float cpl = cosf(ph + lam), spl = sinf(ph + lam);
  o[0] = c;        o[1] = 0.0f;
  o[2] = -cl * s;  o[3] = -sl * s;
  o[4] = cp * s;   o[5] = spv * s;
  o[6] = cpl * c;  o[7] = spl * c;
}

__global__ __launch_bounds__(128) void prep_kernel(
    const float* __restrict__ u3p, const float* __restrict__ cu3p,
    const float* __restrict__ fcw, float* __restrict__ G,
    float* __restrict__ FCW2) {
  __shared__ float Us[40][8];
  __shared__ float Cs[40][8];
  int t = threadIdx.x;
  if (t < 40) u3fill(u3p + t * 3, Us[t]);
  if (t >= 64 && t < 104) u3fill(cu3p + (t - 64) * 3, Cs[t - 64]);
  __syncthreads();
  if (t == 0) {
#pragma unroll
    for (int j = 0; j < 8; ++j) G[j] = Us[0][j];
  } else if (t < 36) {
    int j = t - 1, b = j / 7, k = j % 7;
    float* dst = G + 8 + b * 112 + k * 16;
    const float* U = Us[b * 8 + k + 1];
    const float* C = Cs[b * 8 + k];
#pragma unroll
    for (int q = 0; q < 8; ++q) dst[q] = U[q];
    mm2(C, U, dst + 8);
  } else if (t < 40) {
    int b = t - 36;
    float* dst = G + 568 + b * 16;
    const float* U = Us[(b + 1) * 8];
    const float* C = Cs[b * 8 + 7];
#pragma unroll
    for (int q = 0; q < 8; ++q) dst[q] = U[q];
    mm2(U, C, dst + 8);
  } else if (t == 40) {
#pragma unroll
    for (int j = 0; j < 8; ++j) G[632 + j] = Cs[39][j];
  }
  for (int i = t; i < 768; i += 128) {
    int s = i >> 8, cc = (i >> 3) & 31, wv = i & 7;
    float sc = (s == 0) ? 1.0f : ((s == 1) ? (1.0f / 256.0f) : (1.0f / 65536.0f));
    FCW2[i] = fcw[cc * 24 + s * 8 + wv] * sc;
  }
}

// ---------------------------------------------------------------------------
// Fused conv + qsim, 8 px/wave, pixel-per-16-lanes layout.
// ---------------------------------------------------------------------------
__global__ __launch_bounds__(256) void qconv_kernel(
    const float* __restrict__ x, const float* __restrict__ cw,
    const float* __restrict__ cb, const float* __restrict__ G,
    const float* __restrict__ FCW2, const float* __restrict__ fcb,
    float* __restrict__ out) {
  const int lane = threadIdx.x & 63;
  const int wid = __builtin_amdgcn_readfirstlane(
      (int)((blockIdx.x * blockDim.x + threadIdx.x) >> 6));
  const int p0 = wid * 8;
  const int q = lane & 15;

  float sg[4];
  sg[0] = (q & 8) ? -1.0f : 1.0f;
  sg[1] = (q & 4) ? -1.0f : 1.0f;
  sg[2] = (q & 2) ? -1.0f : 1.0f;
  sg[3] = (q & 1) ? -1.0f : 1.0f;

  // ---- conv: lane = (px = lane>>3, oc = lane&7), full 16-ic accumulation ----
  float ang;
  {
    const int px = lane >> 3;
    const int oc = lane & 7;
    const int p  = p0 + px;
    const int b  = p >> 12;
    const int hh = (p >> 6) & 63;
    const int wim = p & 63;
    float acc = cb[oc];
#pragma unroll 4
    for (int ic = 0; ic < 16; ++ic) {
      const float* wp = cw + (oc * 16 + ic) * 9;
      const float* xp = x + (b * 16 + ic) * 4096;
#pragma unroll
      for (int kh = 0; kh < 3; ++kh) {
        int ih = hh + kh - 1;
        bool rok = (unsigned)ih < 64u;
        int ihc = rok ? ih : 0;
#pragma unroll
        for (int kw = 0; kw < 3; ++kw) {
          int iw = wim + kw - 1;
          bool ok = rok && ((unsigned)iw < 64u);
          int iwc = ((unsigned)iw < 64u) ? iw : 0;
          float xv = xp[ihc * 64 + iwc];
          acc = fmaf(ok ? xv : 0.0f, wp[kh * 3 + kw], acc);
        }
      }
    }
    ang = acc;
  }

  // ---- gather group's 16 angles via bpermute, build packed product state ----
  v2f Sr[16], Si[16];
  {
    const int gb = (lane & 48) << 2;  // group base lane * 4
    float aA[8], aB[8];
#pragma unroll
    for (int w = 0; w < 8; ++w) {
      aA[w] = bperm(ang, gb + (w << 2));
      aB[w] = bperm(ang, gb + ((8 + w) << 2));
    }
    float cA[8], sA[8], cB[8], sB[8];
#pragma unroll
    for (int w = 0; w < 8; ++w) {
      __sincosf(0.5f * aA[w], &sA[w], &cA[w]);
      __sincosf(0.5f * aB[w], &sB[w], &cB[w]);
    }
    float fA = ((q & 8) ? sA[0] : cA[0]) * ((q & 4) ? sA[1] : cA[1])
             * ((q & 2) ? sA[2] : cA[2]) * ((q & 1) ? sA[3] : cA[3]);
    float fB = ((q & 8) ? sB[0] : cB[0]) * ((q & 4) ? sB[1] : cB[1])
             * ((q & 2) ? sB[2] : cB[2]) * ((q & 1) ? sB[3] : cB[3]);
    v2f uu[4], vv[4];
    uu[0].x = cA[6]*cA[7]; uu[1].x = cA[6]*sA[7];
    uu[2].x = sA[6]*cA[7]; uu[3].x = sA[6]*sA[7];
    uu[0].y = cB[6]*cB[7]; uu[1].y = cB[6]*sB[7];
    uu[2].y = sB[6]*cB[7]; uu[3].y = sB[6]*sB[7];
    float vA0 = fA * cA[4], vA1 = fA * sA[4];
    float vB0 = fB * cB[4], vB1 = fB * sB[4];
    vv[0].x = vA0*cA[5]; vv[1].x = vA0*sA[5];
    vv[2].x = vA1*cA[5]; vv[3].x = vA1*sA[5];
    vv[0].y = vB0*cB[5]; vv[1].y = vB0*sB[5];
    vv[2].y = vB1*cB[5]; vv[3].y = vB1*sB[5];
#pragma unroll
    for (int r = 0; r < 16; ++r) {
      Sr[r] = vv[r >> 2] * uu[r & 3];
      Si[r] = sp(0.0f);
    }
  }

  // ---- fused circuit (same algebra/G table as round 3, remapped wires) ----
  crossG<8, 0>(Sr, Si, G, lane);
  for (int b = 0; b < 5; ++b) {
    const float* base = G + 8 + b * 112;
    crossG<4, 8>(Sr, Si, base +  0, lane);   // F1: ctrl w0, tgt w1
    crossG<2, 4>(Sr, Si, base + 16, lane);   // F2
    crossG<1, 2>(Sr, Si, base + 32, lane);   // F3
    f4N(Sr, Si, base + 48, lane);            // F4: ctrl lane bit0, tgt r bit3
    f5N(Sr, Si, base + 64);                  // F5
    f6N(Sr, Si, base + 80);                  // F6
    f7N(Sr, Si, base + 96);                  // F7
    if (b < 4) f8pN(Sr, Si, G + 568 + b * 16, lane);
  }
  f8N(Sr, Si, G + 632, lane);

  // ---- three measurement stages folded into FC ----
  const int j = q & 7;
  const bool isB = (q & 8) != 0;
  float acc[4];
#pragma unroll
  for (int k = 0; k < 4; ++k) acc[k] = fcb[4 * j + k];

  v2f m[8];
  measureN(Sr, Si, sg, m);
  fcN(m, FCW2, isB, j, acc);
  hallN(Sr, Si, sg);
  measureN(Sr, Si, sg, m);
  fcN(m, FCW2 + 256, isB, j, acc);
  phaseYN(Sr, Si, lane);
  hallN(Sr, Si, sg);
  measureN(Sr, Si, sg, m);
  fcN(m, FCW2 + 512, isB, j, acc);

  // ---- store: pixel p0 + 2g + isB, channels 4j..4j+3 ----
  const int g = lane >> 4;
  const int p = p0 + 2 * g + (isB ? 1 : 0);
  const int ob = (p >> 12) * 131072 + (p & 4095);
#pragma unroll
  for (int k = 0; k < 4; ++k)
    out[ob + (4 * j + k) * 4096] = acc[k];
}

extern "C" void kernel_launch(void* const* d_in, const int* in_sizes, int n_in,
                              void* d_out, int out_size, void* d_ws, size_t ws_size,
                              hipStream_t stream) {
  const float* x      = (const float*)d_in[0];
  const float* conv_w = (const float*)d_in[1];
  const float* conv_b = (const float*)d_in[2];
  const float* u3p    = (const float*)d_in[3];
  const float* cu3p   = (const float*)d_in[4];
  const float* fcw    = (const float*)d_in[5];
  const float* fcb    = (const float*)d_in[6];
  float* out = (float*)d_out;

  float* ws   = (float*)d_ws;
  float* G    = ws;          // 640 (fused gate matrices)
  float* FCW2 = ws + 640;    // 768 (stage-major, pre-scaled)

  prep_kernel<<<1, 128, 0, stream>>>(u3p, cu3p, fcw, G, FCW2);
  qconv_kernel<<<512, 256, 0, stream>>>(x, conv_w, conv_b, G, FCW2, fcb, out);
}